// Round 6
// baseline (14995.543 us; speedup 1.0000x reference)
//
#include <hip/hip_runtime.h>
#include <cstdint>
#include <cstddef>

// Transformer forward, 4 layers. B=4, N=1024, D=1024, H=16, DH=64, F=4096.
// Round 5: byte-identical resubmit (4th acquisition timeout; never executed).
//   - Weights: per-launch transpose+split into blocked layout
//     [xtile][ktile][4 kpanels][128 x][8 k] bf16 (hi,lo separate).
//   - Activations produced directly in the same split blocked layout by
//     LN / GELU-epilogue / attention kernels.
//   - GEMM: 128x128 tile, BK=32, 4 waves x 4x4 frags of mfma_f32_16x16x32_bf16,
//     3 MFMA per frag-pair (AhiBhi + AhiBlo + AloBhi), global_load_lds(16B)
//     staging, m97 2-barrier structure. Fused epilogues (qkv scatter fp32,
//     bias+residual fp32, bias+gelu->split).
//   - Attention: fp32 per-q-row online softmax, __shfl P broadcast,
//     writes split blocked output.
// Workspace: 144MB of d_ws (see kernel_launch layout).

#define D_MODEL 1024
#define SEQ     1024
#define BATCH   4
#define HEADS   16
#define DHEAD   64
#define DFF     4096
#define LAYERS  4

typedef unsigned short u16;
typedef __attribute__((ext_vector_type(8))) short s16x8;
typedef __attribute__((ext_vector_type(4))) float f32x4;
typedef __attribute__((ext_vector_type(4))) unsigned short u16x4;

// ---------------------------- helpers ---------------------------------------
__device__ __forceinline__ u16 bf16_rn(float x) {
  uint32_t u = __float_as_uint(x);
  uint32_t r = (u + 0x7fffu + ((u >> 16) & 1u)) >> 16;
  return (u16)r;
}
__device__ __forceinline__ float bf16_f(u16 h) {
  return __uint_as_float((uint32_t)h << 16);
}
__device__ __forceinline__ void split2(float x, u16& hi, u16& lo) {
  hi = bf16_rn(x);
  lo = bf16_rn(x - bf16_f(hi));
}
// blocked split layout: x = the 128-dim (rows for A, cols for B), kk = k dim
__device__ __forceinline__ size_t split_addr(int x, int kk, int KT) {
  return ((size_t)(x >> 7) * KT + (kk >> 5)) * 4096 +
         (size_t)(((kk >> 3) & 3) * 1024 + (x & 127) * 8 + (kk & 7));
}

#define GLDS(gp, lp)                                                           \
  __builtin_amdgcn_global_load_lds(                                            \
      (const __attribute__((address_space(1))) uint32_t*)(gp),                 \
      (__attribute__((address_space(3))) uint32_t*)(lp), 16, 0, 0)

// ------------------------ weight transpose+split -----------------------------
// W [K][N] f32 row-major -> whi/wlo blocked (x=n, kk=k). grid (K/32, N/128).
__global__ __launch_bounds__(256, 4) void wsplit_kernel(
    const float* __restrict__ W, u16* __restrict__ whi, u16* __restrict__ wlo,
    int K, int N)
{
  __shared__ float L[32][129];
  const int kt = blockIdx.x, nt = blockIdx.y;
  const int t = threadIdx.x;
  {
    const int k = t >> 3, nq = (t & 7) * 16;
    const float* src = W + (size_t)(kt * 32 + k) * N + nt * 128 + nq;
#pragma unroll
    for (int i2 = 0; i2 < 4; ++i2) {
      float4 v = *(const float4*)(src + i2 * 4);
      L[k][nq + i2 * 4 + 0] = v.x; L[k][nq + i2 * 4 + 1] = v.y;
      L[k][nq + i2 * 4 + 2] = v.z; L[k][nq + i2 * 4 + 3] = v.w;
    }
  }
  __syncthreads();
  const int n = t & 127, kr0 = t >> 7;
  const size_t tile = ((size_t)nt * (K >> 5) + kt) * 4096;
#pragma unroll
  for (int rr = kr0; rr < 4; rr += 2) {
    s16x8 hv, lv;
#pragma unroll
    for (int j = 0; j < 8; ++j) {
      float x = L[rr * 8 + j][n];
      u16 h_, l_; split2(x, h_, l_);
      hv[j] = (short)h_; lv[j] = (short)l_;
    }
    size_t ad = tile + (size_t)rr * 1024 + (size_t)n * 8;
    *(s16x8*)(whi + ad) = hv;
    *(s16x8*)(wlo + ad) = lv;
  }
}

// ----------------------------- LayerNorm -> split -----------------------------
__global__ __launch_bounds__(256, 8) void ln_split_kernel(
    const float* __restrict__ x, const float* __restrict__ scale,
    const float* __restrict__ shift, u16* __restrict__ hhi, u16* __restrict__ hlo)
{
  const int row = blockIdx.x;
  const int tid = threadIdx.x;
  const float* xr = x + (size_t)row * D_MODEL;
  float4 v = *(const float4*)(xr + tid * 4);
  float s  = v.x + v.y + v.z + v.w;
  float s2 = v.x * v.x + v.y * v.y + v.z * v.z + v.w * v.w;
  for (int o = 32; o; o >>= 1) {
    s  += __shfl_xor(s,  o, 64);
    s2 += __shfl_xor(s2, o, 64);
  }
  __shared__ float rb[8];
  int wave = tid >> 6, lane = tid & 63;
  if (lane == 0) { rb[wave] = s; rb[4 + wave] = s2; }
  __syncthreads();
  float S  = rb[0] + rb[1] + rb[2] + rb[3];
  float S2 = rb[4] + rb[5] + rb[6] + rb[7];
  float mean = S * (1.0f / D_MODEL);
  float var  = S2 * (1.0f / D_MODEL) - mean * mean;
  float rstd = rsqrtf(var + 1e-5f);
  float4 sc = *(const float4*)(scale + tid * 4);
  float4 sh = *(const float4*)(shift + tid * 4);
  float y0 = sc.x * (v.x - mean) * rstd + sh.x;
  float y1 = sc.y * (v.y - mean) * rstd + sh.y;
  float y2 = sc.z * (v.z - mean) * rstd + sh.z;
  float y3 = sc.w * (v.w - mean) * rstd + sh.w;
  int c0 = tid * 4;
  size_t ad = split_addr(row, c0, D_MODEL / 32);
  u16 h0, l0, h1, l1, h2, l2, h3, l3;
  split2(y0, h0, l0); split2(y1, h1, l1);
  split2(y2, h2, l2); split2(y3, h3, l3);
  u16x4 hv = {h0, h1, h2, h3};
  u16x4 lv = {l0, l1, l2, l3};
  *(u16x4*)(hhi + ad) = hv;
  *(u16x4*)(hlo + ad) = lv;
}

// ------------------------------- GEMM (bf16x3) -------------------------------
enum { EPI_QKV = 0, EPI_RES = 1, EPI_GELU = 2 };

template <int EPI>
__global__ __launch_bounds__(256, 2) void gemm_split(
    const u16* __restrict__ Ah_g, const u16* __restrict__ Al_g,
    const u16* __restrict__ Bh_g, const u16* __restrict__ Bl_g,
    const float* __restrict__ bias, float* __restrict__ C,
    int N, int KT,
    float* __restrict__ qb, float* __restrict__ ktb, float* __restrict__ vb,
    u16* __restrict__ ghi, u16* __restrict__ glo)
{
  __shared__ u16 smem[4 * 4096];          // Ahi | Alo | Bhi | Blo, 8KB each
  u16* sAh = smem;
  u16* sAl = smem + 4096;
  u16* sBh = smem + 8192;
  u16* sBl = smem + 12288;
  const int tid = threadIdx.x, w = tid >> 6, lane = tid & 63;
  const int wr = w >> 1, wc = w & 1;
  const int g4 = lane >> 4, l16 = lane & 15;
  const int bx = blockIdx.x, by = blockIdx.y;

  f32x4 acc[4][4];
#pragma unroll
  for (int i = 0; i < 4; ++i)
#pragma unroll
    for (int j = 0; j < 4; ++j) acc[i][j] = (f32x4){0.f, 0.f, 0.f, 0.f};

  const size_t tA0 = (size_t)by * KT, tB0 = (size_t)bx * KT;
  for (int kt = 0; kt < KT; ++kt) {
    __syncthreads();
    const char* gA_h = (const char*)(Ah_g + (tA0 + kt) * 4096);
    const char* gA_l = (const char*)(Al_g + (tA0 + kt) * 4096);
    const char* gB_h = (const char*)(Bh_g + (tB0 + kt) * 4096);
    const char* gB_l = (const char*)(Bl_g + (tB0 + kt) * 4096);
#pragma unroll
    for (int i = 0; i < 2; ++i) {
      const int ofs = (w * 2 + i) * 1024;           // bytes within 8KB tile
      const int lofs = ofs + lane * 16;
      GLDS(gA_h + lofs, (char*)sAh + ofs);
      GLDS(gA_l + lofs, (char*)sAl + ofs);
      GLDS(gB_h + lofs, (char*)sBh + ofs);
      GLDS(gB_l + lofs, (char*)sBl + ofs);
    }
    __syncthreads();

    s16x8 ah[4], al[4], bh[4], bl[4];
    const int ab = g4 * 1024 + (wr * 64 + l16) * 8;
    const int bb = g4 * 1024 + (wc * 64 + l16) * 8;
#pragma unroll
    for (int mf = 0; mf < 4; ++mf) {
      ah[mf] = *(const s16x8*)(sAh + ab + mf * 128);
      al[mf] = *(const s16x8*)(sAl + ab + mf * 128);
    }
#pragma unroll
    for (int nf = 0; nf < 4; ++nf) {
      bh[nf] = *(const s16x8*)(sBh + bb + nf * 128);
      bl[nf] = *(const s16x8*)(sBl + bb + nf * 128);
    }
#pragma unroll
    for (int mf = 0; mf < 4; ++mf)
#pragma unroll
      for (int nf = 0; nf < 4; ++nf) {
        acc[mf][nf] = __builtin_amdgcn_mfma_f32_16x16x32_bf16(
            ah[mf], bh[nf], acc[mf][nf], 0, 0, 0);
        acc[mf][nf] = __builtin_amdgcn_mfma_f32_16x16x32_bf16(
            ah[mf], bl[nf], acc[mf][nf], 0, 0, 0);
        acc[mf][nf] = __builtin_amdgcn_mfma_f32_16x16x32_bf16(
            al[mf], bh[nf], acc[mf][nf], 0, 0, 0);
      }
  }

  // epilogue: D[r][c], r = frag row (lane>>4)*4+reg, c = lane&15   [m89]
  const int r0 = by * 128 + wr * 64;
  const int c0 = bx * 128 + wc * 64;
#pragma unroll
  for (int mf = 0; mf < 4; ++mf) {
#pragma unroll
    for (int nf = 0; nf < 4; ++nf) {
      const int c = c0 + nf * 16 + l16;
      const float bv = bias[c];
#pragma unroll
      for (int reg = 0; reg < 4; ++reg) {
        const int r = r0 + mf * 16 + g4 * 4 + reg;
        float val = acc[mf][nf][reg] + bv;
        if (EPI == EPI_QKV) {
          int b_ = r >> 10, n_ = r & (SEQ - 1);
          int part = c >> 10, cc = c & (D_MODEL - 1);
          int head = cc >> 6, dd = cc & (DHEAD - 1);
          size_t bh_ = (size_t)(b_ * HEADS + head);
          if (part == 0)      qb [(bh_ * SEQ + n_) * DHEAD + dd] = val;
          else if (part == 1) ktb[(bh_ * DHEAD + dd) * SEQ + n_] = val;
          else                vb [(bh_ * SEQ + n_) * DHEAD + dd] = val;
        } else if (EPI == EPI_RES) {
          C[(size_t)r * D_MODEL + c] += val;
        } else {  // EPI_GELU -> split blocked g (KT = DFF/32 = 128)
          float u = val;
          float inner = 0.7978845608028654f * (u + 0.044715f * u * u * u);
          float gv = 0.5f * u * (1.0f + tanhf(inner));
          u16 h_, l_; split2(gv, h_, l_);
          size_t ad = split_addr(r, c, DFF / 32);
          ghi[ad] = h_; glo[ad] = l_;
        }
      }
    }
  }
}

// ----------------------------- Attention (fp32) ------------------------------
__global__ __launch_bounds__(256, 4) void attn_kernel(
    const float* __restrict__ q, const float* __restrict__ kT,
    const float* __restrict__ v, u16* __restrict__ ohi, u16* __restrict__ olo)
{
  int tid = threadIdx.x;
  int wave = tid >> 6, lane = tid & 63;
  int idx = blockIdx.x * 4 + wave;   // 0 .. B*H*N-1
  int i  = idx & (SEQ - 1);          // query row
  int bh = idx >> 10;                // 0..63
  const float* qp = q  + ((size_t)bh * SEQ + i) * DHEAD;
  const float* kb = kT + (size_t)bh * DHEAD * SEQ;
  const float* vp = v  + (size_t)bh * SEQ * DHEAD;

  float qv[DHEAD / 4][4];
#pragma unroll
  for (int t4 = 0; t4 < DHEAD / 4; ++t4) {
    float4 tq = *(const float4*)(qp + t4 * 4);
    qv[t4][0] = tq.x; qv[t4][1] = tq.y; qv[t4][2] = tq.z; qv[t4][3] = tq.w;
  }

  float m = -3.0e38f, l = 0.0f, oacc = 0.0f;
  for (int j0 = 0; j0 <= i; j0 += 64) {
    int j = j0 + lane;
    float s = 0.0f;
#pragma unroll
    for (int t4 = 0; t4 < DHEAD / 4; ++t4)
#pragma unroll
      for (int dd = 0; dd < 4; ++dd)
        s += qv[t4][dd] * kb[(size_t)(t4 * 4 + dd) * SEQ + j];
    s *= 0.125f;                       // 1/sqrt(DH)
    if (j > i) s = -1.0e10f;           // causal mask (matches reference NEG)

    float bm = s;
    for (int o = 32; o; o >>= 1) bm = fmaxf(bm, __shfl_xor(bm, o, 64));
    float m_new = fmaxf(m, bm);
    float corr = expf(m - m_new);
    float p = expf(s - m_new);
    float sp = p;
    for (int o = 32; o; o >>= 1) sp += __shfl_xor(sp, o, 64);
    l = l * corr + sp;
    oacc *= corr;
    int jmax = min(64, i - j0 + 1);
    for (int jj = 0; jj < jmax; ++jj) {
      float pj = __shfl(p, jj, 64);
      oacc += pj * vp[(size_t)(j0 + jj) * DHEAD + lane];
    }
    m = m_new;
  }
  float val = oacc / l;
  int b_ = bh >> 4, h_ = bh & 15;
  int r = b_ * SEQ + i;
  int c = h_ * DHEAD + lane;
  u16 h2, l2; split2(val, h2, l2);
  size_t ad = split_addr(r, c, D_MODEL / 32);
  ohi[ad] = h2; olo[ad] = l2;
}

// ----------------------------- Launch ---------------------------------------
extern "C" void kernel_launch(void* const* d_in, const int* in_sizes, int n_in,
                              void* d_out, int out_size, void* d_ws, size_t ws_size,
                              hipStream_t stream)
{
  const float* x_in  = (const float*)d_in[0];
  // d_in[1] = mask_f (unused; causal mask computed analytically)
  const float* ln1_s = (const float*)d_in[2];
  const float* ln1_b = (const float*)d_in[3];
  const float* qkv_w = (const float*)d_in[4];
  const float* qkv_b = (const float*)d_in[5];
  const float* out_w = (const float*)d_in[6];
  const float* out_b = (const float*)d_in[7];
  const float* ln2_s = (const float*)d_in[8];
  const float* ln2_b = (const float*)d_in[9];
  const float* w1    = (const float*)d_in[10];
  const float* b1    = (const float*)d_in[11];
  const float* w2    = (const float*)d_in[12];
  const float* b2    = (const float*)d_in[13];

  float* x = (float*)d_out;                  // residual stream lives in d_out
  char* wsb = (char*)d_ws;                   // needs >= 144 MB
  const size_t MB = (size_t)1 << 20;
  const size_t MEG = (size_t)1 << 20;        // elems
  u16* whi = (u16*)(wsb + 0);                // 24MB: qkv 3M | out 1M | w1 4M | w2 4M
  u16* wlo = (u16*)(wsb + 24 * MB);
  u16* hhi = (u16*)(wsb + 48 * MB);
  u16* hlo = (u16*)(wsb + 56 * MB);
  u16* ohi = (u16*)(wsb + 64 * MB);
  u16* olo = (u16*)(wsb + 72 * MB);
  float* qb  = (float*)(wsb + 80 * MB);
  float* ktb = (float*)(wsb + 96 * MB);
  float* vb  = (float*)(wsb + 112 * MB);
  u16* ghi = (u16*)(wsb + 80 * MB);          // alias (qb..vb dead by MLP)
  u16* glo = (u16*)(wsb + 112 * MB);

  const size_t OQKV = 0, OOUT = 3 * MEG, OW1 = 4 * MEG, OW2 = 8 * MEG;
  const int T = BATCH * SEQ;  // 4096 rows

  (void)hipMemcpyAsync(x, x_in, (size_t)T * D_MODEL * sizeof(float),
                       hipMemcpyDeviceToDevice, stream);

  for (int lyr = 0; lyr < LAYERS; ++lyr) {
    // --- weight prepass (transpose + split to blocked bf16) ---
    wsplit_kernel<<<dim3(32, 24), 256, 0, stream>>>(
        qkv_w + (size_t)lyr * D_MODEL * 3 * D_MODEL, whi + OQKV, wlo + OQKV,
        D_MODEL, 3 * D_MODEL);
    wsplit_kernel<<<dim3(32, 8), 256, 0, stream>>>(
        out_w + (size_t)lyr * D_MODEL * D_MODEL, whi + OOUT, wlo + OOUT,
        D_MODEL, D_MODEL);
    wsplit_kernel<<<dim3(32, 32), 256, 0, stream>>>(
        w1 + (size_t)lyr * D_MODEL * DFF, whi + OW1, wlo + OW1,
        D_MODEL, DFF);
    wsplit_kernel<<<dim3(128, 8), 256, 0, stream>>>(
        w2 + (size_t)lyr * DFF * D_MODEL, whi + OW2, wlo + OW2,
        DFF, D_MODEL);

    // --- attention sub-block ---
    ln_split_kernel<<<T, 256, 0, stream>>>(x, ln1_s + lyr * D_MODEL,
                                           ln1_b + lyr * D_MODEL, hhi, hlo);
    gemm_split<EPI_QKV><<<dim3(24, 32), 256, 0, stream>>>(
        hhi, hlo, whi + OQKV, wlo + OQKV,
        qkv_b + (size_t)lyr * 3 * D_MODEL, nullptr,
        3 * D_MODEL, D_MODEL / 32, qb, ktb, vb, nullptr, nullptr);
    attn_kernel<<<(BATCH * HEADS * SEQ) / 4, 256, 0, stream>>>(
        qb, ktb, vb, ohi, olo);
    gemm_split<EPI_RES><<<dim3(8, 32), 256, 0, stream>>>(
        ohi, olo, whi + OOUT, wlo + OOUT,
        out_b + (size_t)lyr * D_MODEL, x,
        D_MODEL, D_MODEL / 32, nullptr, nullptr, nullptr, nullptr, nullptr);

    // --- MLP sub-block ---
    ln_split_kernel<<<T, 256, 0, stream>>>(x, ln2_s + lyr * D_MODEL,
                                           ln2_b + lyr * D_MODEL, hhi, hlo);
    gemm_split<EPI_GELU><<<dim3(32, 32), 256, 0, stream>>>(
        hhi, hlo, whi + OW1, wlo + OW1,
        b1 + (size_t)lyr * DFF, nullptr,
        DFF, D_MODEL / 32, nullptr, nullptr, nullptr, ghi, glo);
    gemm_split<EPI_RES><<<dim3(8, 32), 256, 0, stream>>>(
        ghi, glo, whi + OW2, wlo + OW2,
        b2 + (size_t)lyr * D_MODEL, x,
        D_MODEL, DFF / 32, nullptr, nullptr, nullptr, nullptr, nullptr);
  }
}

// Round 7
// 2314.399 us; speedup vs baseline: 6.4792x; 6.4792x over previous
//
#include <hip/hip_runtime.h>
#include <cstdint>
#include <cstddef>

// Transformer forward, 4 layers. B=4, N=1024, D=1024, H=16, DH=64, F=4096.
// Round 6: MFMA flash attention (old attn_kernel was latency-bound: 3.3ms/layer,
// VALUBusy 16%, HBM 0.6%). QKV epilogue now writes Q/K/V^T as bf16 hi/lo
// panel-blocked tensors; attn_mfma does QK^T (bf16x3) + online softmax +
// PV (P bf16, V hi/lo) with 16x16x32 MFMA, K/V staged via global_load_lds.
// GEMM path unchanged from round 5 (bf16x3 split, 128x128 tile, m97 structure).
// Workspace: 144MB of d_ws (see kernel_launch layout).

#define D_MODEL 1024
#define SEQ     1024
#define BATCH   4
#define HEADS   16
#define DHEAD   64
#define DFF     4096
#define LAYERS  4

typedef unsigned short u16;
typedef __attribute__((ext_vector_type(8))) short s16x8;
typedef __attribute__((ext_vector_type(4))) float f32x4;
typedef __attribute__((ext_vector_type(4))) unsigned short u16x4;

// ---------------------------- helpers ---------------------------------------
__device__ __forceinline__ u16 bf16_rn(float x) {
  uint32_t u = __float_as_uint(x);
  uint32_t r = (u + 0x7fffu + ((u >> 16) & 1u)) >> 16;
  return (u16)r;
}
__device__ __forceinline__ float bf16_f(u16 h) {
  return __uint_as_float((uint32_t)h << 16);
}
__device__ __forceinline__ void split2(float x, u16& hi, u16& lo) {
  hi = bf16_rn(x);
  lo = bf16_rn(x - bf16_f(hi));
}
// blocked split layout: x = the 128-dim (rows for A, cols for B), kk = k dim
__device__ __forceinline__ size_t split_addr(int x, int kk, int KT) {
  return ((size_t)(x >> 7) * KT + (kk >> 5)) * 4096 +
         (size_t)(((kk >> 3) & 3) * 1024 + (x & 127) * 8 + (kk & 7));
}

#define GLDS(gp, lp)                                                           \
  __builtin_amdgcn_global_load_lds(                                            \
      (const __attribute__((address_space(1))) uint32_t*)(gp),                 \
      (__attribute__((address_space(3))) uint32_t*)(lp), 16, 0, 0)

// ------------------------ weight transpose+split -----------------------------
// W [K][N] f32 row-major -> whi/wlo blocked (x=n, kk=k). grid (K/32, N/128).
__global__ __launch_bounds__(256, 4) void wsplit_kernel(
    const float* __restrict__ W, u16* __restrict__ whi, u16* __restrict__ wlo,
    int K, int N)
{
  __shared__ float L[32][129];
  const int kt = blockIdx.x, nt = blockIdx.y;
  const int t = threadIdx.x;
  {
    const int k = t >> 3, nq = (t & 7) * 16;
    const float* src = W + (size_t)(kt * 32 + k) * N + nt * 128 + nq;
#pragma unroll
    for (int i2 = 0; i2 < 4; ++i2) {
      float4 v = *(const float4*)(src + i2 * 4);
      L[k][nq + i2 * 4 + 0] = v.x; L[k][nq + i2 * 4 + 1] = v.y;
      L[k][nq + i2 * 4 + 2] = v.z; L[k][nq + i2 * 4 + 3] = v.w;
    }
  }
  __syncthreads();
  const int n = t & 127, kr0 = t >> 7;
  const size_t tile = ((size_t)nt * (K >> 5) + kt) * 4096;
#pragma unroll
  for (int rr = kr0; rr < 4; rr += 2) {
    s16x8 hv, lv;
#pragma unroll
    for (int j = 0; j < 8; ++j) {
      float x = L[rr * 8 + j][n];
      u16 h_, l_; split2(x, h_, l_);
      hv[j] = (short)h_; lv[j] = (short)l_;
    }
    size_t ad = tile + (size_t)rr * 1024 + (size_t)n * 8;
    *(s16x8*)(whi + ad) = hv;
    *(s16x8*)(wlo + ad) = lv;
  }
}

// ----------------------------- LayerNorm -> split -----------------------------
__global__ __launch_bounds__(256, 8) void ln_split_kernel(
    const float* __restrict__ x, const float* __restrict__ scale,
    const float* __restrict__ shift, u16* __restrict__ hhi, u16* __restrict__ hlo)
{
  const int row = blockIdx.x;
  const int tid = threadIdx.x;
  const float* xr = x + (size_t)row * D_MODEL;
  float4 v = *(const float4*)(xr + tid * 4);
  float s  = v.x + v.y + v.z + v.w;
  float s2 = v.x * v.x + v.y * v.y + v.z * v.z + v.w * v.w;
  for (int o = 32; o; o >>= 1) {
    s  += __shfl_xor(s,  o, 64);
    s2 += __shfl_xor(s2, o, 64);
  }
  __shared__ float rb[8];
  int wave = tid >> 6, lane = tid & 63;
  if (lane == 0) { rb[wave] = s; rb[4 + wave] = s2; }
  __syncthreads();
  float S  = rb[0] + rb[1] + rb[2] + rb[3];
  float S2 = rb[4] + rb[5] + rb[6] + rb[7];
  float mean = S * (1.0f / D_MODEL);
  float var  = S2 * (1.0f / D_MODEL) - mean * mean;
  float rstd = rsqrtf(var + 1e-5f);
  float4 sc = *(const float4*)(scale + tid * 4);
  float4 sh = *(const float4*)(shift + tid * 4);
  float y0 = sc.x * (v.x - mean) * rstd + sh.x;
  float y1 = sc.y * (v.y - mean) * rstd + sh.y;
  float y2 = sc.z * (v.z - mean) * rstd + sh.z;
  float y3 = sc.w * (v.w - mean) * rstd + sh.w;
  int c0 = tid * 4;
  size_t ad = split_addr(row, c0, D_MODEL / 32);
  u16 h0, l0, h1, l1, h2, l2, h3, l3;
  split2(y0, h0, l0); split2(y1, h1, l1);
  split2(y2, h2, l2); split2(y3, h3, l3);
  u16x4 hv = {h0, h1, h2, h3};
  u16x4 lv = {l0, l1, l2, l3};
  *(u16x4*)(hhi + ad) = hv;
  *(u16x4*)(hlo + ad) = lv;
}

// ------------------------------- GEMM (bf16x3) -------------------------------
enum { EPI_QKV = 0, EPI_RES = 1, EPI_GELU = 2 };

template <int EPI>
__global__ __launch_bounds__(256, 2) void gemm_split(
    const u16* __restrict__ Ah_g, const u16* __restrict__ Al_g,
    const u16* __restrict__ Bh_g, const u16* __restrict__ Bl_g,
    const float* __restrict__ bias, float* __restrict__ C,
    int N, int KT,
    u16* __restrict__ qhb, u16* __restrict__ qlb,
    u16* __restrict__ khb, u16* __restrict__ klb,
    u16* __restrict__ vthb, u16* __restrict__ vtlb,
    u16* __restrict__ ghi, u16* __restrict__ glo)
{
  __shared__ u16 smem[4 * 4096];          // Ahi | Alo | Bhi | Blo, 8KB each
  u16* sAh = smem;
  u16* sAl = smem + 4096;
  u16* sBh = smem + 8192;
  u16* sBl = smem + 12288;
  const int tid = threadIdx.x, w = tid >> 6, lane = tid & 63;
  const int wr = w >> 1, wc = w & 1;
  const int g4 = lane >> 4, l16 = lane & 15;
  const int bx = blockIdx.x, by = blockIdx.y;

  f32x4 acc[4][4];
#pragma unroll
  for (int i = 0; i < 4; ++i)
#pragma unroll
    for (int j = 0; j < 4; ++j) acc[i][j] = (f32x4){0.f, 0.f, 0.f, 0.f};

  const size_t tA0 = (size_t)by * KT, tB0 = (size_t)bx * KT;
  for (int kt = 0; kt < KT; ++kt) {
    __syncthreads();
    const char* gA_h = (const char*)(Ah_g + (tA0 + kt) * 4096);
    const char* gA_l = (const char*)(Al_g + (tA0 + kt) * 4096);
    const char* gB_h = (const char*)(Bh_g + (tB0 + kt) * 4096);
    const char* gB_l = (const char*)(Bl_g + (tB0 + kt) * 4096);
#pragma unroll
    for (int i = 0; i < 2; ++i) {
      const int ofs = (w * 2 + i) * 1024;           // bytes within 8KB tile
      const int lofs = ofs + lane * 16;
      GLDS(gA_h + lofs, (char*)sAh + ofs);
      GLDS(gA_l + lofs, (char*)sAl + ofs);
      GLDS(gB_h + lofs, (char*)sBh + ofs);
      GLDS(gB_l + lofs, (char*)sBl + ofs);
    }
    __syncthreads();

    s16x8 ah[4], al[4], bh[4], bl[4];
    const int ab = g4 * 1024 + (wr * 64 + l16) * 8;
    const int bb = g4 * 1024 + (wc * 64 + l16) * 8;
#pragma unroll
    for (int mf = 0; mf < 4; ++mf) {
      ah[mf] = *(const s16x8*)(sAh + ab + mf * 128);
      al[mf] = *(const s16x8*)(sAl + ab + mf * 128);
    }
#pragma unroll
    for (int nf = 0; nf < 4; ++nf) {
      bh[nf] = *(const s16x8*)(sBh + bb + nf * 128);
      bl[nf] = *(const s16x8*)(sBl + bb + nf * 128);
    }
#pragma unroll
    for (int mf = 0; mf < 4; ++mf)
#pragma unroll
      for (int nf = 0; nf < 4; ++nf) {
        acc[mf][nf] = __builtin_amdgcn_mfma_f32_16x16x32_bf16(
            ah[mf], bh[nf], acc[mf][nf], 0, 0, 0);
        acc[mf][nf] = __builtin_amdgcn_mfma_f32_16x16x32_bf16(
            ah[mf], bl[nf], acc[mf][nf], 0, 0, 0);
        acc[mf][nf] = __builtin_amdgcn_mfma_f32_16x16x32_bf16(
            al[mf], bh[nf], acc[mf][nf], 0, 0, 0);
      }
  }

  // epilogue: D[r][c], r = frag row (lane>>4)*4+reg, c = lane&15   [m89]
  const int r0 = by * 128 + wr * 64;
  const int c0 = bx * 128 + wc * 64;
#pragma unroll
  for (int mf = 0; mf < 4; ++mf) {
#pragma unroll
    for (int nf = 0; nf < 4; ++nf) {
      const int c = c0 + nf * 16 + l16;
      const float bv = bias[c];
#pragma unroll
      for (int reg = 0; reg < 4; ++reg) {
        const int r = r0 + mf * 16 + g4 * 4 + reg;
        float val = acc[mf][nf][reg] + bv;
        if (EPI == EPI_QKV) {
          // scatter into bf16 hi/lo panel-blocked q / k / vT for attn_mfma
          int b_ = r >> 10, n_ = r & (SEQ - 1);
          int part = c >> 10, cc = c & (D_MODEL - 1);
          int head = cc >> 6, dd = cc & (DHEAD - 1);
          int bh_ = b_ * HEADS + head;
          u16 h_, l_; split2(val, h_, l_);
          size_t base = ((size_t)bh_ * 16 + (n_ >> 6)) * 4096;
          if (part == 0) {
            size_t ad = base + (dd >> 3) * 512 + (n_ & 63) * 8 + (dd & 7);
            qhb[ad] = h_; qlb[ad] = l_;
          } else if (part == 1) {
            size_t ad = base + (dd >> 3) * 512 + (n_ & 63) * 8 + (dd & 7);
            khb[ad] = h_; klb[ad] = l_;
          } else {
            size_t ad = base + ((n_ & 63) >> 3) * 512 + dd * 8 + (n_ & 7);
            vthb[ad] = h_; vtlb[ad] = l_;
          }
        } else if (EPI == EPI_RES) {
          C[(size_t)r * D_MODEL + c] += val;
        } else {  // EPI_GELU -> split blocked g (KT = DFF/32 = 128)
          float u = val;
          float inner = 0.7978845608028654f * (u + 0.044715f * u * u * u);
          float gv = 0.5f * u * (1.0f + tanhf(inner));
          u16 h_, l_; split2(gv, h_, l_);
          size_t ad = split_addr(r, c, DFF / 32);
          ghi[ad] = h_; glo[ad] = l_;
        }
      }
    }
  }
}

// ----------------------- Attention (MFMA flash) ------------------------------
// Grid: BH * SEQ/64 blocks of 256 threads (4 waves). Wave w owns q-rows
// qt*64 + w*16 .. +15. KV tiles of 64 keys staged in LDS (panel-blocked bf16).
// QK^T = bf16x3 (fp32-grade); P bf16 via per-wave LDS bounce; PV = P*(Vhi+Vlo).
__global__ __launch_bounds__(256, 2) void attn_mfma(
    const u16* __restrict__ qh, const u16* __restrict__ ql,
    const u16* __restrict__ kh, const u16* __restrict__ kl,
    const u16* __restrict__ vth, const u16* __restrict__ vtl,
    u16* __restrict__ ohi, u16* __restrict__ olo)
{
  __shared__ u16 skh[4096], skl[4096], svh[4096], svl[4096];
  __shared__ u16 pbuf[4][16 * 72];          // per-wave P bounce, padded stride

  const int tid = threadIdx.x, w = tid >> 6, lane = tid & 63;
  const int g4 = lane >> 4, l16 = lane & 15;
  const int bh = blockIdx.x >> 4, qt = blockIdx.x & 15;

  // Q fragments (A-operand): row = l16 (q row w*16+l16), k = d = g*32+g4*8+j
  const size_t tq = ((size_t)bh * 16 + qt) * 4096;
  s16x8 qhf[2], qlf[2];
#pragma unroll
  for (int g = 0; g < 2; ++g) {
    const int ad = (g * 4 + g4) * 512 + (w * 16 + l16) * 8;
    qhf[g] = *(const s16x8*)(qh + tq + ad);
    qlf[g] = *(const s16x8*)(ql + tq + ad);
  }

  f32x4 acc[4];
#pragma unroll
  for (int df = 0; df < 4; ++df) acc[df] = (f32x4){0.f, 0.f, 0.f, 0.f};
  float m[4] = {-3.0e38f, -3.0e38f, -3.0e38f, -3.0e38f};
  float l[4] = {0.f, 0.f, 0.f, 0.f};

  for (int kt = 0; kt <= qt; ++kt) {
    __syncthreads();
    const size_t tk = ((size_t)bh * 16 + kt) * 4096;
#pragma unroll
    for (int i = 0; i < 2; ++i) {
      const int ofs = (w * 2 + i) * 1024;
      const int lofs = ofs + lane * 16;
      GLDS((const char*)(kh + tk) + lofs, (char*)skh + ofs);
      GLDS((const char*)(kl + tk) + lofs, (char*)skl + ofs);
      GLDS((const char*)(vth + tk) + lofs, (char*)svh + ofs);
      GLDS((const char*)(vtl + tk) + lofs, (char*)svl + ofs);
    }
    __syncthreads();

    // ---- S = Q K^T (bf16x3): col = key = nf*16+l16, row = q = g4*4+reg ----
    f32x4 s[4];
#pragma unroll
    for (int nf = 0; nf < 4; ++nf) {
      s[nf] = (f32x4){0.f, 0.f, 0.f, 0.f};
#pragma unroll
      for (int g = 0; g < 2; ++g) {
        const int kb = (g * 4 + g4) * 512 + (nf * 16 + l16) * 8;
        s16x8 khf = *(const s16x8*)(skh + kb);
        s16x8 klf = *(const s16x8*)(skl + kb);
        s[nf] = __builtin_amdgcn_mfma_f32_16x16x32_bf16(qhf[g], khf, s[nf], 0, 0, 0);
        s[nf] = __builtin_amdgcn_mfma_f32_16x16x32_bf16(qhf[g], klf, s[nf], 0, 0, 0);
        s[nf] = __builtin_amdgcn_mfma_f32_16x16x32_bf16(qlf[g], khf, s[nf], 0, 0, 0);
      }
    }
    // scale + causal mask (diagonal tile only)
    const bool diag = (kt == qt);
    const int qloc = w * 16 + g4 * 4;
#pragma unroll
    for (int nf = 0; nf < 4; ++nf) {
      const int keyl = nf * 16 + l16;
#pragma unroll
      for (int r = 0; r < 4; ++r) {
        float sv = s[nf][r] * 0.125f;
        if (diag && keyl > qloc + r) sv = -1.0e10f;
        s[nf][r] = sv;
      }
    }
    // ---- online softmax (row = reg; reduce across 16-lane group) ----
    float corr[4];
#pragma unroll
    for (int r = 0; r < 4; ++r) {
      float sv = fmaxf(fmaxf(s[0][r], s[1][r]), fmaxf(s[2][r], s[3][r]));
      sv = fmaxf(sv, __shfl_xor(sv, 1, 64));
      sv = fmaxf(sv, __shfl_xor(sv, 2, 64));
      sv = fmaxf(sv, __shfl_xor(sv, 4, 64));
      sv = fmaxf(sv, __shfl_xor(sv, 8, 64));
      float mn = fmaxf(m[r], sv);
      corr[r] = expf(m[r] - mn);
      m[r] = mn;
    }
#pragma unroll
    for (int nf = 0; nf < 4; ++nf)
#pragma unroll
      for (int r = 0; r < 4; ++r)
        s[nf][r] = expf(s[nf][r] - m[r]);
#pragma unroll
    for (int r = 0; r < 4; ++r) {
      float ps = s[0][r] + s[1][r] + s[2][r] + s[3][r];
      ps += __shfl_xor(ps, 1, 64);
      ps += __shfl_xor(ps, 2, 64);
      ps += __shfl_xor(ps, 4, 64);
      ps += __shfl_xor(ps, 8, 64);
      l[r] = l[r] * corr[r] + ps;
    }
#pragma unroll
    for (int df = 0; df < 4; ++df)
#pragma unroll
      for (int r = 0; r < 4; ++r)
        acc[df][r] *= corr[r];

    // ---- P -> bf16, transpose C-frag -> A-frag via per-wave LDS bounce ----
    u16* pb = pbuf[w];
#pragma unroll
    for (int nf = 0; nf < 4; ++nf)
#pragma unroll
      for (int r = 0; r < 4; ++r)
        pb[(g4 * 4 + r) * 72 + nf * 16 + l16] = bf16_rn(s[nf][r]);
    __syncthreads();   // order pbuf writes before cross-lane reads (uniform)
    s16x8 pa[2];
#pragma unroll
    for (int g = 0; g < 2; ++g)
      pa[g] = *(const s16x8*)(pb + l16 * 72 + g * 32 + g4 * 8);

    // ---- O += P * V : col = d = df*16+l16, k = key ----
#pragma unroll
    for (int df = 0; df < 4; ++df)
#pragma unroll
      for (int g = 0; g < 2; ++g) {
        const int vb_ = (g * 4 + g4) * 512 + (df * 16 + l16) * 8;
        s16x8 vhf = *(const s16x8*)(svh + vb_);
        s16x8 vlf = *(const s16x8*)(svl + vb_);
        acc[df] = __builtin_amdgcn_mfma_f32_16x16x32_bf16(pa[g], vhf, acc[df], 0, 0, 0);
        acc[df] = __builtin_amdgcn_mfma_f32_16x16x32_bf16(pa[g], vlf, acc[df], 0, 0, 0);
      }
  }

  // ---- write O (blocked split layout for the out-proj GEMM) ----
  const int b_ = bh >> 4, h_ = bh & 15;
#pragma unroll
  for (int df = 0; df < 4; ++df) {
    const int c = h_ * 64 + df * 16 + l16;
#pragma unroll
    for (int r = 0; r < 4; ++r) {
      const int n_ = qt * 64 + w * 16 + g4 * 4 + r;
      float val = acc[df][r] / l[r];
      u16 h2, l2; split2(val, h2, l2);
      size_t ad = split_addr(b_ * SEQ + n_, c, D_MODEL / 32);
      ohi[ad] = h2; olo[ad] = l2;
    }
  }
}

// ----------------------------- Launch ---------------------------------------
extern "C" void kernel_launch(void* const* d_in, const int* in_sizes, int n_in,
                              void* d_out, int out_size, void* d_ws, size_t ws_size,
                              hipStream_t stream)
{
  const float* x_in  = (const float*)d_in[0];
  // d_in[1] = mask_f (unused; causal mask computed analytically)
  const float* ln1_s = (const float*)d_in[2];
  const float* ln1_b = (const float*)d_in[3];
  const float* qkv_w = (const float*)d_in[4];
  const float* qkv_b = (const float*)d_in[5];
  const float* out_w = (const float*)d_in[6];
  const float* out_b = (const float*)d_in[7];
  const float* ln2_s = (const float*)d_in[8];
  const float* ln2_b = (const float*)d_in[9];
  const float* w1    = (const float*)d_in[10];
  const float* b1    = (const float*)d_in[11];
  const float* w2    = (const float*)d_in[12];
  const float* b2    = (const float*)d_in[13];

  float* x = (float*)d_out;                  // residual stream lives in d_out
  char* wsb = (char*)d_ws;                   // needs >= 144 MB
  const size_t MB = (size_t)1 << 20;
  const size_t MEG = (size_t)1 << 20;        // elems
  u16* whi = (u16*)(wsb + 0);                // 24MB: qkv 3M | out 1M | w1 4M | w2 4M
  u16* wlo = (u16*)(wsb + 24 * MB);
  u16* hhi = (u16*)(wsb + 48 * MB);
  u16* hlo = (u16*)(wsb + 56 * MB);
  u16* ohi = (u16*)(wsb + 64 * MB);
  u16* olo = (u16*)(wsb + 72 * MB);
  // attention tensors: 6 x 8MB bf16 panel-blocked (hi/lo of q, k, vT)
  u16* qhb  = (u16*)(wsb + 80 * MB);
  u16* qlb  = (u16*)(wsb + 88 * MB);
  u16* khb  = (u16*)(wsb + 96 * MB);
  u16* klb  = (u16*)(wsb + 104 * MB);
  u16* vthb = (u16*)(wsb + 112 * MB);
  u16* vtlb = (u16*)(wsb + 120 * MB);
  u16* ghi = (u16*)(wsb + 80 * MB);          // alias (q..vt dead by MLP)
  u16* glo = (u16*)(wsb + 112 * MB);

  const size_t OQKV = 0, OOUT = 3 * MEG, OW1 = 4 * MEG, OW2 = 8 * MEG;
  const int T = BATCH * SEQ;  // 4096 rows

  (void)hipMemcpyAsync(x, x_in, (size_t)T * D_MODEL * sizeof(float),
                       hipMemcpyDeviceToDevice, stream);

  for (int lyr = 0; lyr < LAYERS; ++lyr) {
    // --- weight prepass (transpose + split to blocked bf16) ---
    wsplit_kernel<<<dim3(32, 24), 256, 0, stream>>>(
        qkv_w + (size_t)lyr * D_MODEL * 3 * D_MODEL, whi + OQKV, wlo + OQKV,
        D_MODEL, 3 * D_MODEL);
    wsplit_kernel<<<dim3(32, 8), 256, 0, stream>>>(
        out_w + (size_t)lyr * D_MODEL * D_MODEL, whi + OOUT, wlo + OOUT,
        D_MODEL, D_MODEL);
    wsplit_kernel<<<dim3(32, 32), 256, 0, stream>>>(
        w1 + (size_t)lyr * D_MODEL * DFF, whi + OW1, wlo + OW1,
        D_MODEL, DFF);
    wsplit_kernel<<<dim3(128, 8), 256, 0, stream>>>(
        w2 + (size_t)lyr * DFF * D_MODEL, whi + OW2, wlo + OW2,
        DFF, D_MODEL);

    // --- attention sub-block ---
    ln_split_kernel<<<T, 256, 0, stream>>>(x, ln1_s + lyr * D_MODEL,
                                           ln1_b + lyr * D_MODEL, hhi, hlo);
    gemm_split<EPI_QKV><<<dim3(24, 32), 256, 0, stream>>>(
        hhi, hlo, whi + OQKV, wlo + OQKV,
        qkv_b + (size_t)lyr * 3 * D_MODEL, nullptr,
        3 * D_MODEL, D_MODEL / 32,
        qhb, qlb, khb, klb, vthb, vtlb, nullptr, nullptr);
    attn_mfma<<<BATCH * HEADS * (SEQ / 64), 256, 0, stream>>>(
        qhb, qlb, khb, klb, vthb, vtlb, ohi, olo);
    gemm_split<EPI_RES><<<dim3(8, 32), 256, 0, stream>>>(
        ohi, olo, whi + OOUT, wlo + OOUT,
        out_b + (size_t)lyr * D_MODEL, x,
        D_MODEL, D_MODEL / 32,
        nullptr, nullptr, nullptr, nullptr, nullptr, nullptr, nullptr, nullptr);

    // --- MLP sub-block ---
    ln_split_kernel<<<T, 256, 0, stream>>>(x, ln2_s + lyr * D_MODEL,
                                           ln2_b + lyr * D_MODEL, hhi, hlo);
    gemm_split<EPI_GELU><<<dim3(32, 32), 256, 0, stream>>>(
        hhi, hlo, whi + OW1, wlo + OW1,
        b1 + (size_t)lyr * DFF, nullptr,
        DFF, D_MODEL / 32,
        nullptr, nullptr, nullptr, nullptr, nullptr, nullptr, ghi, glo);
    gemm_split<EPI_RES><<<dim3(8, 32), 256, 0, stream>>>(
        ghi, glo, whi + OW2, wlo + OW2,
        b2 + (size_t)lyr * D_MODEL, x,
        D_MODEL, DFF / 32,
        nullptr, nullptr, nullptr, nullptr, nullptr, nullptr, nullptr, nullptr);
  }
}

// Round 8
// 1951.198 us; speedup vs baseline: 7.6853x; 1.1861x over previous
//
#include <hip/hip_runtime.h>
#include <cstdint>
#include <cstddef>

// Transformer forward, 4 layers. B=4, N=1024, D=1024, H=16, DH=64, F=4096.
// Round 7: stall-bound GEMMs (MfmaUtil 27%, zero stage/compute overlap).
//   + T3-minimum double-buffered LDS prefetch in gemm_split and attn_mfma
//     (STAGE(next) before compute(cur); one barrier per K-step).
//   + T1 XCD-aware block swizzle on all GEMM/attn grids (all nwg % 8 == 0).
//   + GELU via sigmoid identity (__expf), __expf softmax.
// Math unchanged: bf16x3 split GEMMs, bf16x3 QK^T, P bf16, V hi/lo.
// Workspace: 144MB of d_ws (see kernel_launch layout).

#define D_MODEL 1024
#define SEQ     1024
#define BATCH   4
#define HEADS   16
#define DHEAD   64
#define DFF     4096
#define LAYERS  4

typedef unsigned short u16;
typedef __attribute__((ext_vector_type(8))) short s16x8;
typedef __attribute__((ext_vector_type(4))) float f32x4;
typedef __attribute__((ext_vector_type(4))) unsigned short u16x4;

// ---------------------------- helpers ---------------------------------------
__device__ __forceinline__ u16 bf16_rn(float x) {
  uint32_t u = __float_as_uint(x);
  uint32_t r = (u + 0x7fffu + ((u >> 16) & 1u)) >> 16;
  return (u16)r;
}
__device__ __forceinline__ float bf16_f(u16 h) {
  return __uint_as_float((uint32_t)h << 16);
}
__device__ __forceinline__ void split2(float x, u16& hi, u16& lo) {
  hi = bf16_rn(x);
  lo = bf16_rn(x - bf16_f(hi));
}
// blocked split layout: x = the 128-dim (rows for A, cols for B), kk = k dim
__device__ __forceinline__ size_t split_addr(int x, int kk, int KT) {
  return ((size_t)(x >> 7) * KT + (kk >> 5)) * 4096 +
         (size_t)(((kk >> 3) & 3) * 1024 + (x & 127) * 8 + (kk & 7));
}
// T1: XCD-aware swizzle (requires nwg % 8 == 0; all our grids qualify)
__device__ __forceinline__ int xcd_swz_lin(int lin, int nwg) {
  return (lin & 7) * (nwg >> 3) + (lin >> 3);
}

#define GLDS(gp, lp)                                                           \
  __builtin_amdgcn_global_load_lds(                                            \
      (const __attribute__((address_space(1))) uint32_t*)(gp),                 \
      (__attribute__((address_space(3))) uint32_t*)(lp), 16, 0, 0)

// ------------------------ weight transpose+split -----------------------------
// W [K][N] f32 row-major -> whi/wlo blocked (x=n, kk=k). grid (K/32, N/128).
__global__ __launch_bounds__(256, 4) void wsplit_kernel(
    const float* __restrict__ W, u16* __restrict__ whi, u16* __restrict__ wlo,
    int K, int N)
{
  __shared__ float L[32][129];
  const int kt = blockIdx.x, nt = blockIdx.y;
  const int t = threadIdx.x;
  {
    const int k = t >> 3, nq = (t & 7) * 16;
    const float* src = W + (size_t)(kt * 32 + k) * N + nt * 128 + nq;
#pragma unroll
    for (int i2 = 0; i2 < 4; ++i2) {
      float4 v = *(const float4*)(src + i2 * 4);
      L[k][nq + i2 * 4 + 0] = v.x; L[k][nq + i2 * 4 + 1] = v.y;
      L[k][nq + i2 * 4 + 2] = v.z; L[k][nq + i2 * 4 + 3] = v.w;
    }
  }
  __syncthreads();
  const int n = t & 127, kr0 = t >> 7;
  const size_t tile = ((size_t)nt * (K >> 5) + kt) * 4096;
#pragma unroll
  for (int rr = kr0; rr < 4; rr += 2) {
    s16x8 hv, lv;
#pragma unroll
    for (int j = 0; j < 8; ++j) {
      float x = L[rr * 8 + j][n];
      u16 h_, l_; split2(x, h_, l_);
      hv[j] = (short)h_; lv[j] = (short)l_;
    }
    size_t ad = tile + (size_t)rr * 1024 + (size_t)n * 8;
    *(s16x8*)(whi + ad) = hv;
    *(s16x8*)(wlo + ad) = lv;
  }
}

// ----------------------------- LayerNorm -> split -----------------------------
__global__ __launch_bounds__(256, 8) void ln_split_kernel(
    const float* __restrict__ x, const float* __restrict__ scale,
    const float* __restrict__ shift, u16* __restrict__ hhi, u16* __restrict__ hlo)
{
  const int row = blockIdx.x;
  const int tid = threadIdx.x;
  const float* xr = x + (size_t)row * D_MODEL;
  float4 v = *(const float4*)(xr + tid * 4);
  float s  = v.x + v.y + v.z + v.w;
  float s2 = v.x * v.x + v.y * v.y + v.z * v.z + v.w * v.w;
  for (int o = 32; o; o >>= 1) {
    s  += __shfl_xor(s,  o, 64);
    s2 += __shfl_xor(s2, o, 64);
  }
  __shared__ float rb[8];
  int wave = tid >> 6, lane = tid & 63;
  if (lane == 0) { rb[wave] = s; rb[4 + wave] = s2; }
  __syncthreads();
  float S  = rb[0] + rb[1] + rb[2] + rb[3];
  float S2 = rb[4] + rb[5] + rb[6] + rb[7];
  float mean = S * (1.0f / D_MODEL);
  float var  = S2 * (1.0f / D_MODEL) - mean * mean;
  float rstd = rsqrtf(var + 1e-5f);
  float4 sc = *(const float4*)(scale + tid * 4);
  float4 sh = *(const float4*)(shift + tid * 4);
  float y0 = sc.x * (v.x - mean) * rstd + sh.x;
  float y1 = sc.y * (v.y - mean) * rstd + sh.y;
  float y2 = sc.z * (v.z - mean) * rstd + sh.z;
  float y3 = sc.w * (v.w - mean) * rstd + sh.w;
  int c0 = tid * 4;
  size_t ad = split_addr(row, c0, D_MODEL / 32);
  u16 h0, l0, h1, l1, h2, l2, h3, l3;
  split2(y0, h0, l0); split2(y1, h1, l1);
  split2(y2, h2, l2); split2(y3, h3, l3);
  u16x4 hv = {h0, h1, h2, h3};
  u16x4 lv = {l0, l1, l2, l3};
  *(u16x4*)(hhi + ad) = hv;
  *(u16x4*)(hlo + ad) = lv;
}

// ------------------------------- GEMM (bf16x3) -------------------------------
enum { EPI_QKV = 0, EPI_RES = 1, EPI_GELU = 2 };

template <int EPI>
__global__ __launch_bounds__(256, 2) void gemm_split(
    const u16* __restrict__ Ah_g, const u16* __restrict__ Al_g,
    const u16* __restrict__ Bh_g, const u16* __restrict__ Bl_g,
    const float* __restrict__ bias, float* __restrict__ C,
    int N, int KT,
    u16* __restrict__ qhb, u16* __restrict__ qlb,
    u16* __restrict__ khb, u16* __restrict__ klb,
    u16* __restrict__ vthb, u16* __restrict__ vtlb,
    u16* __restrict__ ghi, u16* __restrict__ glo)
{
  __shared__ u16 smem[2][4][4096];        // [dbuf][Ahi|Alo|Bhi|Blo] 8KB each
  const int tid = threadIdx.x, w = tid >> 6, lane = tid & 63;
  const int wr = w >> 1, wc = w & 1;
  const int g4 = lane >> 4, l16 = lane & 15;
  // T1 XCD swizzle
  const int nbx = gridDim.x;
  const int lin = blockIdx.y * nbx + blockIdx.x;
  const int swz = xcd_swz_lin(lin, nbx * gridDim.y);
  const int bx = swz % nbx, by = swz / nbx;

  f32x4 acc[4][4];
#pragma unroll
  for (int i = 0; i < 4; ++i)
#pragma unroll
    for (int j = 0; j < 4; ++j) acc[i][j] = (f32x4){0.f, 0.f, 0.f, 0.f};

  const size_t tA0 = (size_t)by * KT, tB0 = (size_t)bx * KT;

#define GSTAGE(bufi, kti) do {                                                 \
    const char* _gAh = (const char*)(Ah_g + (tA0 + (kti)) * 4096);             \
    const char* _gAl = (const char*)(Al_g + (tA0 + (kti)) * 4096);             \
    const char* _gBh = (const char*)(Bh_g + (tB0 + (kti)) * 4096);             \
    const char* _gBl = (const char*)(Bl_g + (tB0 + (kti)) * 4096);             \
    _Pragma("unroll")                                                          \
    for (int _i = 0; _i < 2; ++_i) {                                           \
      const int _ofs = (w * 2 + _i) * 1024;                                    \
      const int _lofs = _ofs + lane * 16;                                      \
      GLDS(_gAh + _lofs, (char*)smem[bufi][0] + _ofs);                         \
      GLDS(_gAl + _lofs, (char*)smem[bufi][1] + _ofs);                         \
      GLDS(_gBh + _lofs, (char*)smem[bufi][2] + _ofs);                         \
      GLDS(_gBl + _lofs, (char*)smem[bufi][3] + _ofs);                         \
    }                                                                          \
  } while (0)

  GSTAGE(0, 0);
  __syncthreads();
  for (int kt = 0; kt < KT; ++kt) {
    const int cur = kt & 1;
    if (kt + 1 < KT) GSTAGE(cur ^ 1, kt + 1);   // prefetch flies under MFMA

    const u16* sAh = smem[cur][0];
    const u16* sAl = smem[cur][1];
    const u16* sBh = smem[cur][2];
    const u16* sBl = smem[cur][3];
    s16x8 ah[4], al[4], bh[4], bl[4];
    const int ab = g4 * 1024 + (wr * 64 + l16) * 8;
    const int bb = g4 * 1024 + (wc * 64 + l16) * 8;
#pragma unroll
    for (int mf = 0; mf < 4; ++mf) {
      ah[mf] = *(const s16x8*)(sAh + ab + mf * 128);
      al[mf] = *(const s16x8*)(sAl + ab + mf * 128);
    }
#pragma unroll
    for (int nf = 0; nf < 4; ++nf) {
      bh[nf] = *(const s16x8*)(sBh + bb + nf * 128);
      bl[nf] = *(const s16x8*)(sBl + bb + nf * 128);
    }
#pragma unroll
    for (int mf = 0; mf < 4; ++mf)
#pragma unroll
      for (int nf = 0; nf < 4; ++nf) {
        acc[mf][nf] = __builtin_amdgcn_mfma_f32_16x16x32_bf16(
            ah[mf], bh[nf], acc[mf][nf], 0, 0, 0);
        acc[mf][nf] = __builtin_amdgcn_mfma_f32_16x16x32_bf16(
            ah[mf], bl[nf], acc[mf][nf], 0, 0, 0);
        acc[mf][nf] = __builtin_amdgcn_mfma_f32_16x16x32_bf16(
            al[mf], bh[nf], acc[mf][nf], 0, 0, 0);
      }
    __syncthreads();   // drains vmcnt (next tile staged) + protects overwrite
  }
#undef GSTAGE

  // epilogue: D[r][c], r = frag row (lane>>4)*4+reg, c = lane&15   [m89]
  const int r0 = by * 128 + wr * 64;
  const int c0 = bx * 128 + wc * 64;
#pragma unroll
  for (int mf = 0; mf < 4; ++mf) {
#pragma unroll
    for (int nf = 0; nf < 4; ++nf) {
      const int c = c0 + nf * 16 + l16;
      const float bv = bias[c];
#pragma unroll
      for (int reg = 0; reg < 4; ++reg) {
        const int r = r0 + mf * 16 + g4 * 4 + reg;
        float val = acc[mf][nf][reg] + bv;
        if (EPI == EPI_QKV) {
          // scatter into bf16 hi/lo panel-blocked q / k / vT for attn_mfma
          int b_ = r >> 10, n_ = r & (SEQ - 1);
          int part = c >> 10, cc = c & (D_MODEL - 1);
          int head = cc >> 6, dd = cc & (DHEAD - 1);
          int bh_ = b_ * HEADS + head;
          u16 h_, l_; split2(val, h_, l_);
          size_t base = ((size_t)bh_ * 16 + (n_ >> 6)) * 4096;
          if (part == 0) {
            size_t ad = base + (dd >> 3) * 512 + (n_ & 63) * 8 + (dd & 7);
            qhb[ad] = h_; qlb[ad] = l_;
          } else if (part == 1) {
            size_t ad = base + (dd >> 3) * 512 + (n_ & 63) * 8 + (dd & 7);
            khb[ad] = h_; klb[ad] = l_;
          } else {
            size_t ad = base + ((n_ & 63) >> 3) * 512 + dd * 8 + (n_ & 7);
            vthb[ad] = h_; vtlb[ad] = l_;
          }
        } else if (EPI == EPI_RES) {
          C[(size_t)r * D_MODEL + c] += val;
        } else {  // EPI_GELU -> split blocked g (KT = DFF/32 = 128)
          float u = val;
          float z = 1.5957691216057308f * (u + 0.044715f * u * u * u);
          float gv = u / (1.0f + __expf(-z));   // == 0.5u(1+tanh(z/2))
          u16 h_, l_; split2(gv, h_, l_);
          size_t ad = split_addr(r, c, DFF / 32);
          ghi[ad] = h_; glo[ad] = l_;
        }
      }
    }
  }
}

// ----------------------- Attention (MFMA flash) ------------------------------
// Grid: BH * SEQ/64 blocks of 256 threads (4 waves). Wave w owns q-rows
// qt*64 + w*16 .. +15. KV tiles of 64 keys double-buffered in LDS.
// QK^T = bf16x3 (fp32-grade); P bf16 via per-wave LDS bounce; PV = P*(Vhi+Vlo).
__global__ __launch_bounds__(256, 2) void attn_mfma(
    const u16* __restrict__ qh, const u16* __restrict__ ql,
    const u16* __restrict__ kh, const u16* __restrict__ kl,
    const u16* __restrict__ vth, const u16* __restrict__ vtl,
    u16* __restrict__ ohi, u16* __restrict__ olo)
{
  __shared__ u16 skv[2][4][4096];           // [dbuf][Khi|Klo|Vhi|Vlo]
  __shared__ u16 pbuf[4][16 * 72];          // per-wave P bounce, padded stride

  const int tid = threadIdx.x, w = tid >> 6, lane = tid & 63;
  const int g4 = lane >> 4, l16 = lane & 15;
  const int swzb = xcd_swz_lin(blockIdx.x, gridDim.x);   // T1
  const int bh = swzb >> 4, qt = swzb & 15;

  // Q fragments (A-operand): row = l16 (q row w*16+l16), k = d = g*32+g4*8+j
  const size_t tq = ((size_t)bh * 16 + qt) * 4096;
  s16x8 qhf[2], qlf[2];
#pragma unroll
  for (int g = 0; g < 2; ++g) {
    const int ad = (g * 4 + g4) * 512 + (w * 16 + l16) * 8;
    qhf[g] = *(const s16x8*)(qh + tq + ad);
    qlf[g] = *(const s16x8*)(ql + tq + ad);
  }

  f32x4 acc[4];
#pragma unroll
  for (int df = 0; df < 4; ++df) acc[df] = (f32x4){0.f, 0.f, 0.f, 0.f};
  float m[4] = {-3.0e38f, -3.0e38f, -3.0e38f, -3.0e38f};
  float l[4] = {0.f, 0.f, 0.f, 0.f};

#define KVSTAGE(bufi, kti) do {                                                \
    const size_t _tk = ((size_t)bh * 16 + (kti)) * 4096;                       \
    _Pragma("unroll")                                                          \
    for (int _i = 0; _i < 2; ++_i) {                                           \
      const int _ofs = (w * 2 + _i) * 1024;                                    \
      const int _lofs = _ofs + lane * 16;                                      \
      GLDS((const char*)(kh + _tk) + _lofs, (char*)skv[bufi][0] + _ofs);       \
      GLDS((const char*)(kl + _tk) + _lofs, (char*)skv[bufi][1] + _ofs);       \
      GLDS((const char*)(vth + _tk) + _lofs, (char*)skv[bufi][2] + _ofs);      \
      GLDS((const char*)(vtl + _tk) + _lofs, (char*)skv[bufi][3] + _ofs);      \
    }                                                                          \
  } while (0)

  KVSTAGE(0, 0);
  __syncthreads();
  for (int kt = 0; kt <= qt; ++kt) {
    const int cur = kt & 1;
    if (kt < qt) KVSTAGE(cur ^ 1, kt + 1);   // prefetch under QK^T+softmax

    // ---- S = Q K^T (bf16x3): col = key = nf*16+l16, row = q = g4*4+reg ----
    const u16* skh = skv[cur][0];
    const u16* skl = skv[cur][1];
    f32x4 s[4];
#pragma unroll
    for (int nf = 0; nf < 4; ++nf) {
      s[nf] = (f32x4){0.f, 0.f, 0.f, 0.f};
#pragma unroll
      for (int g = 0; g < 2; ++g) {
        const int kb = (g * 4 + g4) * 512 + (nf * 16 + l16) * 8;
        s16x8 khf = *(const s16x8*)(skh + kb);
        s16x8 klf = *(const s16x8*)(skl + kb);
        s[nf] = __builtin_amdgcn_mfma_f32_16x16x32_bf16(qhf[g], khf, s[nf], 0, 0, 0);
        s[nf] = __builtin_amdgcn_mfma_f32_16x16x32_bf16(qhf[g], klf, s[nf], 0, 0, 0);
        s[nf] = __builtin_amdgcn_mfma_f32_16x16x32_bf16(qlf[g], khf, s[nf], 0, 0, 0);
      }
    }
    // scale + causal mask (diagonal tile only)
    const bool diag = (kt == qt);
    const int qloc = w * 16 + g4 * 4;
#pragma unroll
    for (int nf = 0; nf < 4; ++nf) {
      const int keyl = nf * 16 + l16;
#pragma unroll
      for (int r = 0; r < 4; ++r) {
        float sv = s[nf][r] * 0.125f;
        if (diag && keyl > qloc + r) sv = -1.0e10f;
        s[nf][r] = sv;
      }
    }
    // ---- online softmax (row = reg; reduce across 16-lane group) ----
    float corr[4];
#pragma unroll
    for (int r = 0; r < 4; ++r) {
      float sv = fmaxf(fmaxf(s[0][r], s[1][r]), fmaxf(s[2][r], s[3][r]));
      sv = fmaxf(sv, __shfl_xor(sv, 1, 64));
      sv = fmaxf(sv, __shfl_xor(sv, 2, 64));
      sv = fmaxf(sv, __shfl_xor(sv, 4, 64));
      sv = fmaxf(sv, __shfl_xor(sv, 8, 64));
      float mn = fmaxf(m[r], sv);
      corr[r] = __expf(m[r] - mn);
      m[r] = mn;
    }
#pragma unroll
    for (int nf = 0; nf < 4; ++nf)
#pragma unroll
      for (int r = 0; r < 4; ++r)
        s[nf][r] = __expf(s[nf][r] - m[r]);
#pragma unroll
    for (int r = 0; r < 4; ++r) {
      float ps = s[0][r] + s[1][r] + s[2][r] + s[3][r];
      ps += __shfl_xor(ps, 1, 64);
      ps += __shfl_xor(ps, 2, 64);
      ps += __shfl_xor(ps, 4, 64);
      ps += __shfl_xor(ps, 8, 64);
      l[r] = l[r] * corr[r] + ps;
    }
#pragma unroll
    for (int df = 0; df < 4; ++df)
#pragma unroll
      for (int r = 0; r < 4; ++r)
        acc[df][r] *= corr[r];

    // ---- P -> bf16, transpose C-frag -> A-frag via per-wave LDS bounce ----
    u16* pb = pbuf[w];
#pragma unroll
    for (int nf = 0; nf < 4; ++nf)
#pragma unroll
      for (int r = 0; r < 4; ++r)
        pb[(g4 * 4 + r) * 72 + nf * 16 + l16] = bf16_rn(s[nf][r]);
    __syncthreads();   // pbuf ordering (also completes prefetch)
    s16x8 pa[2];
#pragma unroll
    for (int g = 0; g < 2; ++g)
      pa[g] = *(const s16x8*)(pb + l16 * 72 + g * 32 + g4 * 8);

    // ---- O += P * V : col = d = df*16+l16, k = key ----
    const u16* svh = skv[cur][2];
    const u16* svl = skv[cur][3];
#pragma unroll
    for (int df = 0; df < 4; ++df)
#pragma unroll
      for (int g = 0; g < 2; ++g) {
        const int vb_ = (g * 4 + g4) * 512 + (df * 16 + l16) * 8;
        s16x8 vhf = *(const s16x8*)(svh + vb_);
        s16x8 vlf = *(const s16x8*)(svl + vb_);
        acc[df] = __builtin_amdgcn_mfma_f32_16x16x32_bf16(pa[g], vhf, acc[df], 0, 0, 0);
        acc[df] = __builtin_amdgcn_mfma_f32_16x16x32_bf16(pa[g], vlf, acc[df], 0, 0, 0);
      }
    __syncthreads();   // all PV reads of cur done before next STAGE overwrites
  }
#undef KVSTAGE

  // ---- write O (blocked split layout for the out-proj GEMM) ----
  const int b_ = bh >> 4, h_ = bh & 15;
#pragma unroll
  for (int df = 0; df < 4; ++df) {
    const int c = h_ * 64 + df * 16 + l16;
#pragma unroll
    for (int r = 0; r < 4; ++r) {
      const int n_ = qt * 64 + w * 16 + g4 * 4 + r;
      float val = acc[df][r] / l[r];
      u16 h2, l2; split2(val, h2, l2);
      size_t ad = split_addr(b_ * SEQ + n_, c, D_MODEL / 32);
      ohi[ad] = h2; olo[ad] = l2;
    }
  }
}

// ----------------------------- Launch ---------------------------------------
extern "C" void kernel_launch(void* const* d_in, const int* in_sizes, int n_in,
                              void* d_out, int out_size, void* d_ws, size_t ws_size,
                              hipStream_t stream)
{
  const float* x_in  = (const float*)d_in[0];
  // d_in[1] = mask_f (unused; causal mask computed analytically)
  const float* ln1_s = (const float*)d_in[2];
  const float* ln1_b = (const float*)d_in[3];
  const float* qkv_w = (const float*)d_in[4];
  const float* qkv_b = (const float*)d_in[5];
  const float* out_w = (const float*)d_in[6];
  const float* out_b = (const float*)d_in[7];
  const float* ln2_s = (const float*)d_in[8];
  const float* ln2_b = (const float*)d_in[9];
  const float* w1    = (const float*)d_in[10];
  const float* b1    = (const float*)d_in[11];
  const float* w2    = (const float*)d_in[12];
  const float* b2    = (const float*)d_in[13];

  float* x = (float*)d_out;                  // residual stream lives in d_out
  char* wsb = (char*)d_ws;                   // needs >= 144 MB
  const size_t MB = (size_t)1 << 20;
  const size_t MEG = (size_t)1 << 20;        // elems
  u16* whi = (u16*)(wsb + 0);                // 24MB: qkv 3M | out 1M | w1 4M | w2 4M
  u16* wlo = (u16*)(wsb + 24 * MB);
  u16* hhi = (u16*)(wsb + 48 * MB);
  u16* hlo = (u16*)(wsb + 56 * MB);
  u16* ohi = (u16*)(wsb + 64 * MB);
  u16* olo = (u16*)(wsb + 72 * MB);
  // attention tensors: 6 x 8MB bf16 panel-blocked (hi/lo of q, k, vT)
  u16* qhb  = (u16*)(wsb + 80 * MB);
  u16* qlb  = (u16*)(wsb + 88 * MB);
  u16* khb  = (u16*)(wsb + 96 * MB);
  u16* klb  = (u16*)(wsb + 104 * MB);
  u16* vthb = (u16*)(wsb + 112 * MB);
  u16* vtlb = (u16*)(wsb + 120 * MB);
  u16* ghi = (u16*)(wsb + 80 * MB);          // alias (q..vt dead by MLP)
  u16* glo = (u16*)(wsb + 112 * MB);

  const size_t OQKV = 0, OOUT = 3 * MEG, OW1 = 4 * MEG, OW2 = 8 * MEG;
  const int T = BATCH * SEQ;  // 4096 rows

  (void)hipMemcpyAsync(x, x_in, (size_t)T * D_MODEL * sizeof(float),
                       hipMemcpyDeviceToDevice, stream);

  for (int lyr = 0; lyr < LAYERS; ++lyr) {
    // --- weight prepass (transpose + split to blocked bf16) ---
    wsplit_kernel<<<dim3(32, 24), 256, 0, stream>>>(
        qkv_w + (size_t)lyr * D_MODEL * 3 * D_MODEL, whi + OQKV, wlo + OQKV,
        D_MODEL, 3 * D_MODEL);
    wsplit_kernel<<<dim3(32, 8), 256, 0, stream>>>(
        out_w + (size_t)lyr * D_MODEL * D_MODEL, whi + OOUT, wlo + OOUT,
        D_MODEL, D_MODEL);
    wsplit_kernel<<<dim3(32, 32), 256, 0, stream>>>(
        w1 + (size_t)lyr * D_MODEL * DFF, whi + OW1, wlo + OW1,
        D_MODEL, DFF);
    wsplit_kernel<<<dim3(128, 8), 256, 0, stream>>>(
        w2 + (size_t)lyr * DFF * D_MODEL, whi + OW2, wlo + OW2,
        DFF, D_MODEL);

    // --- attention sub-block ---
    ln_split_kernel<<<T, 256, 0, stream>>>(x, ln1_s + lyr * D_MODEL,
                                           ln1_b + lyr * D_MODEL, hhi, hlo);
    gemm_split<EPI_QKV><<<dim3(24, 32), 256, 0, stream>>>(
        hhi, hlo, whi + OQKV, wlo + OQKV,
        qkv_b + (size_t)lyr * 3 * D_MODEL, nullptr,
        3 * D_MODEL, D_MODEL / 32,
        qhb, qlb, khb, klb, vthb, vtlb, nullptr, nullptr);
    attn_mfma<<<BATCH * HEADS * (SEQ / 64), 256, 0, stream>>>(
        qhb, qlb, khb, klb, vthb, vtlb, ohi, olo);
    gemm_split<EPI_RES><<<dim3(8, 32), 256, 0, stream>>>(
        ohi, olo, whi + OOUT, wlo + OOUT,
        out_b + (size_t)lyr * D_MODEL, x,
        D_MODEL, D_MODEL / 32,
        nullptr, nullptr, nullptr, nullptr, nullptr, nullptr, nullptr, nullptr);

    // --- MLP sub-block ---
    ln_split_kernel<<<T, 256, 0, stream>>>(x, ln2_s + lyr * D_MODEL,
                                           ln2_b + lyr * D_MODEL, hhi, hlo);
    gemm_split<EPI_GELU><<<dim3(32, 32), 256, 0, stream>>>(
        hhi, hlo, whi + OW1, wlo + OW1,
        b1 + (size_t)lyr * DFF, nullptr,
        DFF, D_MODEL / 32,
        nullptr, nullptr, nullptr, nullptr, nullptr, nullptr, ghi, glo);
    gemm_split<EPI_RES><<<dim3(8, 32), 256, 0, stream>>>(
        ghi, glo, whi + OW2, wlo + OW2,
        b2 + (size_t)lyr * D_MODEL, x,
        D_MODEL, DFF / 32,
        nullptr, nullptr, nullptr, nullptr, nullptr, nullptr, nullptr, nullptr);
  }
}

// Round 11
// 1599.210 us; speedup vs baseline: 9.3768x; 1.2201x over previous
//
#include <hip/hip_runtime.h>
#include <cstdint>
#include <cstddef>

// Transformer forward, 4 layers. B=4, N=1024, D=1024, H=16, DH=64, F=4096.
// Round 11: byte-identical resubmit of round 9/10 (two acquisition timeouts).
//   + 2-term split (A exact via hi+lo, weights bf16-hi only): -33% MFMA,
//     -25% LDS reads, LDS 64->48KB => 3 blocks/CU. wsplit drops lo.
//   + attn QBLK=128: two q-tiles per block share one K/V staging pass.
// Revert plan: TERMS template arg back to 3 per-GEMM if absmax fails.
// Workspace: 144MB of d_ws (see kernel_launch layout).

#define D_MODEL 1024
#define SEQ     1024
#define BATCH   4
#define HEADS   16
#define DHEAD   64
#define DFF     4096
#define LAYERS  4

typedef unsigned short u16;
typedef __attribute__((ext_vector_type(8))) short s16x8;
typedef __attribute__((ext_vector_type(4))) float f32x4;
typedef __attribute__((ext_vector_type(4))) unsigned short u16x4;

// ---------------------------- helpers ---------------------------------------
__device__ __forceinline__ u16 bf16_rn(float x) {
  uint32_t u = __float_as_uint(x);
  uint32_t r = (u + 0x7fffu + ((u >> 16) & 1u)) >> 16;
  return (u16)r;
}
__device__ __forceinline__ float bf16_f(u16 h) {
  return __uint_as_float((uint32_t)h << 16);
}
__device__ __forceinline__ void split2(float x, u16& hi, u16& lo) {
  hi = bf16_rn(x);
  lo = bf16_rn(x - bf16_f(hi));
}
// blocked split layout: x = the 128-dim (rows for A, cols for B), kk = k dim
__device__ __forceinline__ size_t split_addr(int x, int kk, int KT) {
  return ((size_t)(x >> 7) * KT + (kk >> 5)) * 4096 +
         (size_t)(((kk >> 3) & 3) * 1024 + (x & 127) * 8 + (kk & 7));
}
// T1: XCD-aware swizzle (requires nwg % 8 == 0; all our grids qualify)
__device__ __forceinline__ int xcd_swz_lin(int lin, int nwg) {
  return (lin & 7) * (nwg >> 3) + (lin >> 3);
}

#define GLDS(gp, lp)                                                           \
  __builtin_amdgcn_global_load_lds(                                            \
      (const __attribute__((address_space(1))) uint32_t*)(gp),                 \
      (__attribute__((address_space(3))) uint32_t*)(lp), 16, 0, 0)

// ------------------------ weight transpose (hi only) -------------------------
// W [K][N] f32 row-major -> whi blocked (x=n, kk=k). grid (K/32, N/128).
__global__ __launch_bounds__(256, 4) void wsplit_kernel(
    const float* __restrict__ W, u16* __restrict__ whi, int K, int N)
{
  __shared__ float L[32][129];
  const int kt = blockIdx.x, nt = blockIdx.y;
  const int t = threadIdx.x;
  {
    const int k = t >> 3, nq = (t & 7) * 16;
    const float* src = W + (size_t)(kt * 32 + k) * N + nt * 128 + nq;
#pragma unroll
    for (int i2 = 0; i2 < 4; ++i2) {
      float4 v = *(const float4*)(src + i2 * 4);
      L[k][nq + i2 * 4 + 0] = v.x; L[k][nq + i2 * 4 + 1] = v.y;
      L[k][nq + i2 * 4 + 2] = v.z; L[k][nq + i2 * 4 + 3] = v.w;
    }
  }
  __syncthreads();
  const int n = t & 127, kr0 = t >> 7;
  const size_t tile = ((size_t)nt * (K >> 5) + kt) * 4096;
#pragma unroll
  for (int rr = kr0; rr < 4; rr += 2) {
    s16x8 hv;
#pragma unroll
    for (int j = 0; j < 8; ++j) hv[j] = (short)bf16_rn(L[rr * 8 + j][n]);
    *(s16x8*)(whi + tile + (size_t)rr * 1024 + (size_t)n * 8) = hv;
  }
}

// ----------------------------- LayerNorm -> split -----------------------------
__global__ __launch_bounds__(256, 8) void ln_split_kernel(
    const float* __restrict__ x, const float* __restrict__ scale,
    const float* __restrict__ shift, u16* __restrict__ hhi, u16* __restrict__ hlo)
{
  const int row = blockIdx.x;
  const int tid = threadIdx.x;
  const float* xr = x + (size_t)row * D_MODEL;
  float4 v = *(const float4*)(xr + tid * 4);
  float s  = v.x + v.y + v.z + v.w;
  float s2 = v.x * v.x + v.y * v.y + v.z * v.z + v.w * v.w;
  for (int o = 32; o; o >>= 1) {
    s  += __shfl_xor(s,  o, 64);
    s2 += __shfl_xor(s2, o, 64);
  }
  __shared__ float rb[8];
  int wave = tid >> 6, lane = tid & 63;
  if (lane == 0) { rb[wave] = s; rb[4 + wave] = s2; }
  __syncthreads();
  float S  = rb[0] + rb[1] + rb[2] + rb[3];
  float S2 = rb[4] + rb[5] + rb[6] + rb[7];
  float mean = S * (1.0f / D_MODEL);
  float var  = S2 * (1.0f / D_MODEL) - mean * mean;
  float rstd = rsqrtf(var + 1e-5f);
  float4 sc = *(const float4*)(scale + tid * 4);
  float4 sh = *(const float4*)(shift + tid * 4);
  float y0 = sc.x * (v.x - mean) * rstd + sh.x;
  float y1 = sc.y * (v.y - mean) * rstd + sh.y;
  float y2 = sc.z * (v.z - mean) * rstd + sh.z;
  float y3 = sc.w * (v.w - mean) * rstd + sh.w;
  int c0 = tid * 4;
  size_t ad = split_addr(row, c0, D_MODEL / 32);
  u16 h0, l0, h1, l1, h2, l2, h3, l3;
  split2(y0, h0, l0); split2(y1, h1, l1);
  split2(y2, h2, l2); split2(y3, h3, l3);
  u16x4 hv = {h0, h1, h2, h3};
  u16x4 lv = {l0, l1, l2, l3};
  *(u16x4*)(hhi + ad) = hv;
  *(u16x4*)(hlo + ad) = lv;
}

// --------------------------- GEMM (A exact x B-hi) ---------------------------
enum { EPI_QKV = 0, EPI_RES = 1, EPI_GELU = 2 };

template <int EPI, int TERMS>
__global__ __launch_bounds__(256, 3) void gemm_split(
    const u16* __restrict__ Ah_g, const u16* __restrict__ Al_g,
    const u16* __restrict__ Bh_g, const u16* __restrict__ Bl_g,
    const float* __restrict__ bias, float* __restrict__ C,
    int N, int KT,
    u16* __restrict__ qhb, u16* __restrict__ qlb,
    u16* __restrict__ khb, u16* __restrict__ klb,
    u16* __restrict__ vthb, u16* __restrict__ vtlb,
    u16* __restrict__ ghi, u16* __restrict__ glo)
{
  __shared__ u16 smem[2][(TERMS == 3) ? 4 : 3][4096];  // Ah|Al|Bh[|Bl] 8KB each
  const int tid = threadIdx.x, w = tid >> 6, lane = tid & 63;
  const int wr = w >> 1, wc = w & 1;
  const int g4 = lane >> 4, l16 = lane & 15;
  // T1 XCD swizzle
  const int nbx = gridDim.x;
  const int lin = blockIdx.y * nbx + blockIdx.x;
  const int swz = xcd_swz_lin(lin, nbx * gridDim.y);
  const int bx = swz % nbx, by = swz / nbx;

  f32x4 acc[4][4];
#pragma unroll
  for (int i = 0; i < 4; ++i)
#pragma unroll
    for (int j = 0; j < 4; ++j) acc[i][j] = (f32x4){0.f, 0.f, 0.f, 0.f};

  const size_t tA0 = (size_t)by * KT, tB0 = (size_t)bx * KT;

#define GSTAGE(bufi, kti) do {                                                 \
    const char* _gAh = (const char*)(Ah_g + (tA0 + (kti)) * 4096);             \
    const char* _gAl = (const char*)(Al_g + (tA0 + (kti)) * 4096);             \
    const char* _gBh = (const char*)(Bh_g + (tB0 + (kti)) * 4096);             \
    _Pragma("unroll")                                                          \
    for (int _i = 0; _i < 2; ++_i) {                                           \
      const int _ofs = (w * 2 + _i) * 1024;                                    \
      const int _lofs = _ofs + lane * 16;                                      \
      GLDS(_gAh + _lofs, (char*)smem[bufi][0] + _ofs);                         \
      GLDS(_gAl + _lofs, (char*)smem[bufi][1] + _ofs);                         \
      GLDS(_gBh + _lofs, (char*)smem[bufi][2] + _ofs);                         \
      if (TERMS == 3) {                                                        \
        const char* _gBl = (const char*)(Bl_g + (tB0 + (kti)) * 4096);         \
        GLDS(_gBl + _lofs, (char*)smem[bufi][TERMS] + _ofs);                   \
      }                                                                        \
    }                                                                          \
  } while (0)

  GSTAGE(0, 0);
  __syncthreads();
  for (int kt = 0; kt < KT; ++kt) {
    const int cur = kt & 1;
    if (kt + 1 < KT) GSTAGE(cur ^ 1, kt + 1);   // prefetch flies under MFMA

    const u16* sAh = smem[cur][0];
    const u16* sAl = smem[cur][1];
    const u16* sBh = smem[cur][2];
    s16x8 ah[4], al[4], bh[4];
    const int ab = g4 * 1024 + (wr * 64 + l16) * 8;
    const int bb = g4 * 1024 + (wc * 64 + l16) * 8;
#pragma unroll
    for (int mf = 0; mf < 4; ++mf) {
      ah[mf] = *(const s16x8*)(sAh + ab + mf * 128);
      al[mf] = *(const s16x8*)(sAl + ab + mf * 128);
    }
#pragma unroll
    for (int nf = 0; nf < 4; ++nf)
      bh[nf] = *(const s16x8*)(sBh + bb + nf * 128);
#pragma unroll
    for (int mf = 0; mf < 4; ++mf)
#pragma unroll
      for (int nf = 0; nf < 4; ++nf) {
        acc[mf][nf] = __builtin_amdgcn_mfma_f32_16x16x32_bf16(
            ah[mf], bh[nf], acc[mf][nf], 0, 0, 0);
        acc[mf][nf] = __builtin_amdgcn_mfma_f32_16x16x32_bf16(
            al[mf], bh[nf], acc[mf][nf], 0, 0, 0);
        if (TERMS == 3) {
          const u16* sBl = smem[cur][TERMS == 3 ? 3 : 2];
          s16x8 bl = *(const s16x8*)(sBl + bb + nf * 128);
          acc[mf][nf] = __builtin_amdgcn_mfma_f32_16x16x32_bf16(
              ah[mf], bl, acc[mf][nf], 0, 0, 0);
        }
      }
    __syncthreads();   // drains vmcnt (next tile staged) + protects overwrite
  }
#undef GSTAGE

  // epilogue: D[r][c], r = frag row (lane>>4)*4+reg, c = lane&15   [m89]
  const int r0 = by * 128 + wr * 64;
  const int c0 = bx * 128 + wc * 64;
#pragma unroll
  for (int mf = 0; mf < 4; ++mf) {
#pragma unroll
    for (int nf = 0; nf < 4; ++nf) {
      const int c = c0 + nf * 16 + l16;
      const float bv = bias[c];
#pragma unroll
      for (int reg = 0; reg < 4; ++reg) {
        const int r = r0 + mf * 16 + g4 * 4 + reg;
        float val = acc[mf][nf][reg] + bv;
        if (EPI == EPI_QKV) {
          // scatter into bf16 hi/lo panel-blocked q / k / vT for attn_mfma
          int b_ = r >> 10, n_ = r & (SEQ - 1);
          int part = c >> 10, cc = c & (D_MODEL - 1);
          int head = cc >> 6, dd = cc & (DHEAD - 1);
          int bh_ = b_ * HEADS + head;
          u16 h_, l_; split2(val, h_, l_);
          size_t base = ((size_t)bh_ * 16 + (n_ >> 6)) * 4096;
          if (part == 0) {
            size_t ad = base + (dd >> 3) * 512 + (n_ & 63) * 8 + (dd & 7);
            qhb[ad] = h_; qlb[ad] = l_;
          } else if (part == 1) {
            size_t ad = base + (dd >> 3) * 512 + (n_ & 63) * 8 + (dd & 7);
            khb[ad] = h_; klb[ad] = l_;
          } else {
            size_t ad = base + ((n_ & 63) >> 3) * 512 + dd * 8 + (n_ & 7);
            vthb[ad] = h_; vtlb[ad] = l_;
          }
        } else if (EPI == EPI_RES) {
          C[(size_t)r * D_MODEL + c] += val;
        } else {  // EPI_GELU -> split blocked g (KT = DFF/32 = 128)
          float u = val;
          float z = 1.5957691216057308f * (u + 0.044715f * u * u * u);
          float gv = u / (1.0f + __expf(-z));   // == 0.5u(1+tanh(z/2))
          u16 h_, l_; split2(gv, h_, l_);
          size_t ad = split_addr(r, c, DFF / 32);
          ghi[ad] = h_; glo[ad] = l_;
        }
      }
    }
  }
}

// ----------------------- Attention (MFMA flash, QBLK=128) --------------------
// Grid: BH * SEQ/128 blocks of 256 threads (4 waves). Each block owns two
// adjacent 64-row q-tiles (qta, qtb) sharing one K/V staging pass. Wave w owns
// rows w*16..+15 of each tile. QK^T = bf16x3; P bf16; PV = P*(Vhi+Vlo).
__global__ __launch_bounds__(256, 2) void attn_mfma(
    const u16* __restrict__ qh, const u16* __restrict__ ql,
    const u16* __restrict__ kh, const u16* __restrict__ kl,
    const u16* __restrict__ vth, const u16* __restrict__ vtl,
    u16* __restrict__ ohi, u16* __restrict__ olo)
{
  __shared__ u16 skv[2][4][4096];           // [dbuf][Khi|Klo|Vhi|Vlo]
  __shared__ u16 pbuf[4][16 * 72];          // per-wave P bounce, padded stride

  const int tid = threadIdx.x, w = tid >> 6, lane = tid & 63;
  const int g4 = lane >> 4, l16 = lane & 15;
  const int swzb = xcd_swz_lin(blockIdx.x, gridDim.x);   // T1 (512 blocks)
  const int bh = swzb >> 3, qt2 = swzb & 7;
  const int qta = qt2 * 2, qtb = qt2 * 2 + 1;

  // Q fragments (A-operand): row = l16, k = d = g*32+g4*8+j
  s16x8 qhfA[2], qlfA[2], qhfB[2], qlfB[2];
  {
    const size_t tqa = ((size_t)bh * 16 + qta) * 4096;
    const size_t tqb = ((size_t)bh * 16 + qtb) * 4096;
#pragma unroll
    for (int g = 0; g < 2; ++g) {
      const int ad = (g * 4 + g4) * 512 + (w * 16 + l16) * 8;
      qhfA[g] = *(const s16x8*)(qh + tqa + ad);
      qlfA[g] = *(const s16x8*)(ql + tqa + ad);
      qhfB[g] = *(const s16x8*)(qh + tqb + ad);
      qlfB[g] = *(const s16x8*)(ql + tqb + ad);
    }
  }

  f32x4 accA[4], accB[4];
#pragma unroll
  for (int df = 0; df < 4; ++df) {
    accA[df] = (f32x4){0.f, 0.f, 0.f, 0.f};
    accB[df] = (f32x4){0.f, 0.f, 0.f, 0.f};
  }
  float mA[4] = {-3.0e38f, -3.0e38f, -3.0e38f, -3.0e38f};
  float lA[4] = {0.f, 0.f, 0.f, 0.f};
  float mB[4] = {-3.0e38f, -3.0e38f, -3.0e38f, -3.0e38f};
  float lB[4] = {0.f, 0.f, 0.f, 0.f};

#define KVSTAGE(bufi, kti) do {                                                \
    const size_t _tk = ((size_t)bh * 16 + (kti)) * 4096;                       \
    _Pragma("unroll")                                                          \
    for (int _i = 0; _i < 2; ++_i) {                                           \
      const int _ofs = (w * 2 + _i) * 1024;                                    \
      const int _lofs = _ofs + lane * 16;                                      \
      GLDS((const char*)(kh + _tk) + _lofs, (char*)skv[bufi][0] + _ofs);       \
      GLDS((const char*)(kl + _tk) + _lofs, (char*)skv[bufi][1] + _ofs);       \
      GLDS((const char*)(vth + _tk) + _lofs, (char*)skv[bufi][2] + _ofs);      \
      GLDS((const char*)(vtl + _tk) + _lofs, (char*)skv[bufi][3] + _ofs);      \
    }                                                                          \
  } while (0)

  // One q-group's full tile step: QK^T -> mask -> online softmax -> PV
#define PROCESS(QHF, QLF, ACC, MM, LL, DIAG) do {                              \
    f32x4 s[4];                                                                \
    _Pragma("unroll")                                                          \
    for (int nf = 0; nf < 4; ++nf) {                                           \
      s[nf] = (f32x4){0.f, 0.f, 0.f, 0.f};                                     \
      _Pragma("unroll")                                                        \
      for (int g = 0; g < 2; ++g) {                                            \
        const int kb = (g * 4 + g4) * 512 + (nf * 16 + l16) * 8;               \
        s16x8 khf = *(const s16x8*)(skh + kb);                                 \
        s16x8 klf = *(const s16x8*)(skl + kb);                                 \
        s[nf] = __builtin_amdgcn_mfma_f32_16x16x32_bf16(QHF[g], khf, s[nf], 0, 0, 0); \
        s[nf] = __builtin_amdgcn_mfma_f32_16x16x32_bf16(QHF[g], klf, s[nf], 0, 0, 0); \
        s[nf] = __builtin_amdgcn_mfma_f32_16x16x32_bf16(QLF[g], khf, s[nf], 0, 0, 0); \
      }                                                                        \
    }                                                                          \
    const int qloc = w * 16 + g4 * 4;                                          \
    _Pragma("unroll")                                                          \
    for (int nf = 0; nf < 4; ++nf) {                                           \
      const int keyl = nf * 16 + l16;                                          \
      _Pragma("unroll")                                                        \
      for (int r = 0; r < 4; ++r) {                                            \
        float sv = s[nf][r] * 0.125f;                                          \
        if ((DIAG) && keyl > qloc + r) sv = -1.0e10f;                          \
        s[nf][r] = sv;                                                         \
      }                                                                        \
    }                                                                          \
    float corr[4];                                                             \
    _Pragma("unroll")                                                          \
    for (int r = 0; r < 4; ++r) {                                              \
      float sv = fmaxf(fmaxf(s[0][r], s[1][r]), fmaxf(s[2][r], s[3][r]));      \
      sv = fmaxf(sv, __shfl_xor(sv, 1, 64));                                   \
      sv = fmaxf(sv, __shfl_xor(sv, 2, 64));                                   \
      sv = fmaxf(sv, __shfl_xor(sv, 4, 64));                                   \
      sv = fmaxf(sv, __shfl_xor(sv, 8, 64));                                   \
      float mn = fmaxf(MM[r], sv);                                             \
      corr[r] = __expf(MM[r] - mn);                                            \
      MM[r] = mn;                                                              \
    }                                                                          \
    _Pragma("unroll")                                                          \
    for (int nf = 0; nf < 4; ++nf)                                             \
      _Pragma("unroll")                                                        \
      for (int r = 0; r < 4; ++r)                                              \
        s[nf][r] = __expf(s[nf][r] - MM[r]);                                   \
    _Pragma("unroll")                                                          \
    for (int r = 0; r < 4; ++r) {                                              \
      float ps = s[0][r] + s[1][r] + s[2][r] + s[3][r];                        \
      ps += __shfl_xor(ps, 1, 64);                                             \
      ps += __shfl_xor(ps, 2, 64);                                             \
      ps += __shfl_xor(ps, 4, 64);                                             \
      ps += __shfl_xor(ps, 8, 64);                                             \
      LL[r] = LL[r] * corr[r] + ps;                                            \
    }                                                                          \
    _Pragma("unroll")                                                          \
    for (int df = 0; df < 4; ++df)                                             \
      _Pragma("unroll")                                                        \
      for (int r = 0; r < 4; ++r)                                              \
        ACC[df][r] *= corr[r];                                                 \
    u16* pb = pbuf[w];                                                         \
    _Pragma("unroll")                                                          \
    for (int nf = 0; nf < 4; ++nf)                                             \
      _Pragma("unroll")                                                        \
      for (int r = 0; r < 4; ++r)                                              \
        pb[(g4 * 4 + r) * 72 + nf * 16 + l16] = bf16_rn(s[nf][r]);             \
    __syncthreads();                                                           \
    s16x8 pa[2];                                                               \
    _Pragma("unroll")                                                          \
    for (int g = 0; g < 2; ++g)                                                \
      pa[g] = *(const s16x8*)(pb + l16 * 72 + g * 32 + g4 * 8);                \
    _Pragma("unroll")                                                          \
    for (int df = 0; df < 4; ++df)                                             \
      _Pragma("unroll")                                                        \
      for (int g = 0; g < 2; ++g) {                                            \
        const int vb_ = (g * 4 + g4) * 512 + (df * 16 + l16) * 8;              \
        s16x8 vhf = *(const s16x8*)(svh + vb_);                                \
        s16x8 vlf = *(const s16x8*)(svl + vb_);                                \
        ACC[df] = __builtin_amdgcn_mfma_f32_16x16x32_bf16(pa[g], vhf, ACC[df], 0, 0, 0); \
        ACC[df] = __builtin_amdgcn_mfma_f32_16x16x32_bf16(pa[g], vlf, ACC[df], 0, 0, 0); \
      }                                                                        \
  } while (0)

  KVSTAGE(0, 0);
  __syncthreads();
  for (int kt = 0; kt <= qtb; ++kt) {
    const int cur = kt & 1;
    if (kt < qtb) KVSTAGE(cur ^ 1, kt + 1);   // prefetch under compute

    const u16* skh = skv[cur][0];
    const u16* skl = skv[cur][1];
    const u16* svh = skv[cur][2];
    const u16* svl = skv[cur][3];

    if (kt <= qta)   // block-uniform branch
      PROCESS(qhfA, qlfA, accA, mA, lA, kt == qta);
    PROCESS(qhfB, qlfB, accB, mB, lB, kt == qtb);
    __syncthreads();   // all reads of cur done before next STAGE overwrites
  }
#undef KVSTAGE
#undef PROCESS

  // ---- write O (blocked split layout for the out-proj GEMM) ----
  const int b_ = bh >> 4, h_ = bh & 15;
#pragma unroll
  for (int df = 0; df < 4; ++df) {
    const int c = h_ * 64 + df * 16 + l16;
#pragma unroll
    for (int r = 0; r < 4; ++r) {
      const int rr = w * 16 + g4 * 4 + r;
      {
        const int n_ = qta * 64 + rr;
        float val = accA[df][r] / lA[r];
        u16 h2, l2; split2(val, h2, l2);
        size_t ad = split_addr(b_ * SEQ + n_, c, D_MODEL / 32);
        ohi[ad] = h2; olo[ad] = l2;
      }
      {
        const int n_ = qtb * 64 + rr;
        float val = accB[df][r] / lB[r];
        u16 h2, l2; split2(val, h2, l2);
        size_t ad = split_addr(b_ * SEQ + n_, c, D_MODEL / 32);
        ohi[ad] = h2; olo[ad] = l2;
      }
    }
  }
}

// ----------------------------- Launch ---------------------------------------
extern "C" void kernel_launch(void* const* d_in, const int* in_sizes, int n_in,
                              void* d_out, int out_size, void* d_ws, size_t ws_size,
                              hipStream_t stream)
{
  const float* x_in  = (const float*)d_in[0];
  // d_in[1] = mask_f (unused; causal mask computed analytically)
  const float* ln1_s = (const float*)d_in[2];
  const float* ln1_b = (const float*)d_in[3];
  const float* qkv_w = (const float*)d_in[4];
  const float* qkv_b = (const float*)d_in[5];
  const float* out_w = (const float*)d_in[6];
  const float* out_b = (const float*)d_in[7];
  const float* ln2_s = (const float*)d_in[8];
  const float* ln2_b = (const float*)d_in[9];
  const float* w1    = (const float*)d_in[10];
  const float* b1    = (const float*)d_in[11];
  const float* w2    = (const float*)d_in[12];
  const float* b2    = (const float*)d_in[13];

  float* x = (float*)d_out;                  // residual stream lives in d_out
  char* wsb = (char*)d_ws;                   // needs >= 144 MB
  const size_t MB = (size_t)1 << 20;
  const size_t MEG = (size_t)1 << 20;        // elems
  u16* whi = (u16*)(wsb + 0);                // 24MB: qkv 3M | out 1M | w1 4M | w2 4M
  u16* hhi = (u16*)(wsb + 48 * MB);
  u16* hlo = (u16*)(wsb + 56 * MB);
  u16* ohi = (u16*)(wsb + 64 * MB);
  u16* olo = (u16*)(wsb + 72 * MB);
  // attention tensors: 6 x 8MB bf16 panel-blocked (hi/lo of q, k, vT)
  u16* qhb  = (u16*)(wsb + 80 * MB);
  u16* qlb  = (u16*)(wsb + 88 * MB);
  u16* khb  = (u16*)(wsb + 96 * MB);
  u16* klb  = (u16*)(wsb + 104 * MB);
  u16* vthb = (u16*)(wsb + 112 * MB);
  u16* vtlb = (u16*)(wsb + 120 * MB);
  u16* ghi = (u16*)(wsb + 80 * MB);          // alias (q..vt dead by MLP)
  u16* glo = (u16*)(wsb + 112 * MB);

  const size_t OQKV = 0, OOUT = 3 * MEG, OW1 = 4 * MEG, OW2 = 8 * MEG;
  const int T = BATCH * SEQ;  // 4096 rows

  (void)hipMemcpyAsync(x, x_in, (size_t)T * D_MODEL * sizeof(float),
                       hipMemcpyDeviceToDevice, stream);

  for (int lyr = 0; lyr < LAYERS; ++lyr) {
    // --- weight prepass (transpose to blocked bf16 hi) ---
    wsplit_kernel<<<dim3(32, 24), 256, 0, stream>>>(
        qkv_w + (size_t)lyr * D_MODEL * 3 * D_MODEL, whi + OQKV,
        D_MODEL, 3 * D_MODEL);
    wsplit_kernel<<<dim3(32, 8), 256, 0, stream>>>(
        out_w + (size_t)lyr * D_MODEL * D_MODEL, whi + OOUT,
        D_MODEL, D_MODEL);
    wsplit_kernel<<<dim3(32, 32), 256, 0, stream>>>(
        w1 + (size_t)lyr * D_MODEL * DFF, whi + OW1,
        D_MODEL, DFF);
    wsplit_kernel<<<dim3(128, 8), 256, 0, stream>>>(
        w2 + (size_t)lyr * DFF * D_MODEL, whi + OW2,
        DFF, D_MODEL);

    // --- attention sub-block ---
    ln_split_kernel<<<T, 256, 0, stream>>>(x, ln1_s + lyr * D_MODEL,
                                           ln1_b + lyr * D_MODEL, hhi, hlo);
    gemm_split<EPI_QKV, 2><<<dim3(24, 32), 256, 0, stream>>>(
        hhi, hlo, whi + OQKV, nullptr,
        qkv_b + (size_t)lyr * 3 * D_MODEL, nullptr,
        3 * D_MODEL, D_MODEL / 32,
        qhb, qlb, khb, klb, vthb, vtlb, nullptr, nullptr);
    attn_mfma<<<BATCH * HEADS * (SEQ / 128), 256, 0, stream>>>(
        qhb, qlb, khb, klb, vthb, vtlb, ohi, olo);
    gemm_split<EPI_RES, 2><<<dim3(8, 32), 256, 0, stream>>>(
        ohi, olo, whi + OOUT, nullptr,
        out_b + (size_t)lyr * D_MODEL, x,
        D_MODEL, D_MODEL / 32,
        nullptr, nullptr, nullptr, nullptr, nullptr, nullptr, nullptr, nullptr);

    // --- MLP sub-block ---
    ln_split_kernel<<<T, 256, 0, stream>>>(x, ln2_s + lyr * D_MODEL,
                                           ln2_b + lyr * D_MODEL, hhi, hlo);
    gemm_split<EPI_GELU, 2><<<dim3(32, 32), 256, 0, stream>>>(
        hhi, hlo, whi + OW1, nullptr,
        b1 + (size_t)lyr * DFF, nullptr,
        DFF, D_MODEL / 32,
        nullptr, nullptr, nullptr, nullptr, nullptr, nullptr, ghi, glo);
    gemm_split<EPI_RES, 2><<<dim3(8, 32), 256, 0, stream>>>(
        ghi, glo, whi + OW2, nullptr,
        b2 + (size_t)lyr * D_MODEL, x,
        D_MODEL, DFF / 32,
        nullptr, nullptr, nullptr, nullptr, nullptr, nullptr, nullptr, nullptr);
  }
}